// Round 1
// baseline (2427.914 us; speedup 1.0000x reference)
//
#include <hip/hip_runtime.h>

#define BB   4
#define NQ   2500
#define CC   256
#define HH   8
#define PP   8
#define DFFN 512
#define DH   32
#define BEV  200
#define NVAL (BEV * BEV)

// ---------------------------------------------------------------------------
// elementwise add (float4)
// ---------------------------------------------------------------------------
__global__ __launch_bounds__(256) void add_vec(const float* __restrict__ a,
                                               const float* __restrict__ b,
                                               float* __restrict__ o, int n4) {
    int i = blockIdx.x * 256 + threadIdx.x;
    if (i < n4) {
        float4 av = reinterpret_cast<const float4*>(a)[i];
        float4 bv = reinterpret_cast<const float4*>(b)[i];
        float4 ov;
        ov.x = av.x + bv.x; ov.y = av.y + bv.y;
        ov.z = av.z + bv.z; ov.w = av.w + bv.w;
        reinterpret_cast<float4*>(o)[i] = ov;
    }
}

// ---------------------------------------------------------------------------
// generic tiled GEMM:  C[M,N] = A[M,K] @ W[N,K]^T + bias[N]   (optional ReLU)
// BM=BN=64, BK=16, 256 threads, 4x4 microtile per thread.
// N must be a multiple of 64 (true for all calls: 64/128/256/512).
// ---------------------------------------------------------------------------
#define BM 64
#define BN 64
#define BK 16
template <bool RELU>
__global__ __launch_bounds__(256) void gemm_bias(const float* __restrict__ A,
                                                 const float* __restrict__ W,
                                                 const float* __restrict__ bias,
                                                 float* __restrict__ C,
                                                 int M, int N, int K) {
    __shared__ float As[BK][BM + 4];   // +4 keeps float4 alignment (272B rows)
    __shared__ float Ws[BK][BN + 4];
    const int m0 = blockIdx.y * BM;
    const int n0 = blockIdx.x * BN;
    const int t  = threadIdx.x;
    const int tx = t & 15;       // n dir
    const int ty = t >> 4;       // m dir
    const int lrow = t >> 2;     // 0..63
    const int lk   = (t & 3) << 2;

    float acc[4][4];
#pragma unroll
    for (int i = 0; i < 4; i++)
#pragma unroll
        for (int j = 0; j < 4; j++) acc[i][j] = 0.f;

    const bool aok = (m0 + lrow) < M;
    const float* Ap = A + (size_t)(m0 + lrow) * K + lk;
    const float* Wp = W + (size_t)(n0 + lrow) * K + lk;

    for (int k0 = 0; k0 < K; k0 += BK) {
        float4 av = make_float4(0.f, 0.f, 0.f, 0.f);
        if (aok) av = *reinterpret_cast<const float4*>(Ap + k0);
        float4 wv = *reinterpret_cast<const float4*>(Wp + k0);
        As[lk + 0][lrow] = av.x; As[lk + 1][lrow] = av.y;
        As[lk + 2][lrow] = av.z; As[lk + 3][lrow] = av.w;
        Ws[lk + 0][lrow] = wv.x; Ws[lk + 1][lrow] = wv.y;
        Ws[lk + 2][lrow] = wv.z; Ws[lk + 3][lrow] = wv.w;
        __syncthreads();
#pragma unroll
        for (int kk = 0; kk < BK; kk++) {
            float4 a4 = *reinterpret_cast<const float4*>(&As[kk][ty << 2]);
            float4 w4 = *reinterpret_cast<const float4*>(&Ws[kk][tx << 2]);
            acc[0][0] = fmaf(a4.x, w4.x, acc[0][0]);
            acc[0][1] = fmaf(a4.x, w4.y, acc[0][1]);
            acc[0][2] = fmaf(a4.x, w4.z, acc[0][2]);
            acc[0][3] = fmaf(a4.x, w4.w, acc[0][3]);
            acc[1][0] = fmaf(a4.y, w4.x, acc[1][0]);
            acc[1][1] = fmaf(a4.y, w4.y, acc[1][1]);
            acc[1][2] = fmaf(a4.y, w4.z, acc[1][2]);
            acc[1][3] = fmaf(a4.y, w4.w, acc[1][3]);
            acc[2][0] = fmaf(a4.z, w4.x, acc[2][0]);
            acc[2][1] = fmaf(a4.z, w4.y, acc[2][1]);
            acc[2][2] = fmaf(a4.z, w4.z, acc[2][2]);
            acc[2][3] = fmaf(a4.z, w4.w, acc[2][3]);
            acc[3][0] = fmaf(a4.w, w4.x, acc[3][0]);
            acc[3][1] = fmaf(a4.w, w4.y, acc[3][1]);
            acc[3][2] = fmaf(a4.w, w4.z, acc[3][2]);
            acc[3][3] = fmaf(a4.w, w4.w, acc[3][3]);
        }
        __syncthreads();
    }

    float4 b4 = *reinterpret_cast<const float4*>(bias + n0 + (tx << 2));
#pragma unroll
    for (int i = 0; i < 4; i++) {
        int row = m0 + (ty << 2) + i;
        if (row < M) {
            float4 o;
            o.x = acc[i][0] + b4.x; o.y = acc[i][1] + b4.y;
            o.z = acc[i][2] + b4.z; o.w = acc[i][3] + b4.w;
            if (RELU) {
                o.x = fmaxf(o.x, 0.f); o.y = fmaxf(o.y, 0.f);
                o.z = fmaxf(o.z, 0.f); o.w = fmaxf(o.w, 0.f);
            }
            *reinterpret_cast<float4*>(C + (size_t)row * N + n0 + (tx << 2)) = o;
        }
    }
}

// ---------------------------------------------------------------------------
// flash self-attention, fp32, DH=32, one q-row per thread.
// grid: (ceil(NQ/256), B*H).  Q/K/V layout: (B, NQ, H*DH).
// ---------------------------------------------------------------------------
#define KT 64
__global__ __launch_bounds__(256, 2) void flash_attn(const float* __restrict__ Q,
                                                     const float* __restrict__ Kb,
                                                     const float* __restrict__ Vb,
                                                     float* __restrict__ O) {
    __shared__ float Ks[KT][32];   // rows 128B -> float4 aligned, writes 2-way (free)
    __shared__ float Vs[KT][32];
    const int bh = blockIdx.y;
    const int b = bh >> 3, h = bh & 7;
    const int t = threadIdx.x;
    const int qi = blockIdx.x * 256 + t;
    const int qrow = qi < NQ ? qi : NQ - 1;
    const float scale = 0.17677669529663687f;   // 1/sqrt(32)

    const float* qp = Q + ((size_t)b * NQ + qrow) * CC + h * DH;
    float qreg[DH];
#pragma unroll
    for (int d = 0; d < DH; d++) qreg[d] = qp[d] * scale;

    float m = -1e30f, l = 0.f;
    float acc[DH];
#pragma unroll
    for (int d = 0; d < DH; d++) acc[d] = 0.f;

    const size_t kvbase = (size_t)b * NQ * CC + (size_t)h * DH;

    for (int k0 = 0; k0 < NQ; k0 += KT) {
        const int rem = NQ - k0;
        __syncthreads();
#pragma unroll
        for (int it = 0; it < (KT * DH) / 256; it++) {
            int idx = it * 256 + t;
            int r = idx >> 5, d = idx & 31;
            int kr = k0 + r;
            float kk = 0.f, vv = 0.f;
            if (kr < NQ) {
                size_t g = kvbase + (size_t)kr * CC + d;
                kk = Kb[g]; vv = Vb[g];
            }
            Ks[r][d] = kk; Vs[r][d] = vv;
        }
        __syncthreads();

        float s[KT];
#pragma unroll
        for (int j = 0; j < KT; j++) {
            float sum = 0.f;
#pragma unroll
            for (int d4 = 0; d4 < 8; d4++) {
                float4 k4 = *reinterpret_cast<const float4*>(&Ks[j][d4 << 2]);
                sum = fmaf(qreg[d4 * 4 + 0], k4.x, sum);
                sum = fmaf(qreg[d4 * 4 + 1], k4.y, sum);
                sum = fmaf(qreg[d4 * 4 + 2], k4.z, sum);
                sum = fmaf(qreg[d4 * 4 + 3], k4.w, sum);
            }
            s[j] = sum;
        }
        if (rem < KT) {
#pragma unroll
            for (int j = 0; j < KT; j++)
                if (j >= rem) s[j] = -1e30f;
        }

        float tm = m;
#pragma unroll
        for (int j = 0; j < KT; j++) tm = fmaxf(tm, s[j]);
        float cor = __expf(m - tm);
        m = tm;
        l *= cor;
#pragma unroll
        for (int d = 0; d < DH; d++) acc[d] *= cor;

#pragma unroll
        for (int j = 0; j < KT; j++) {
            float p = __expf(s[j] - m);
            l += p;
#pragma unroll
            for (int d4 = 0; d4 < 8; d4++) {
                float4 v4 = *reinterpret_cast<const float4*>(&Vs[j][d4 << 2]);
                acc[d4 * 4 + 0] = fmaf(p, v4.x, acc[d4 * 4 + 0]);
                acc[d4 * 4 + 1] = fmaf(p, v4.y, acc[d4 * 4 + 1]);
                acc[d4 * 4 + 2] = fmaf(p, v4.z, acc[d4 * 4 + 2]);
                acc[d4 * 4 + 3] = fmaf(p, v4.w, acc[d4 * 4 + 3]);
            }
        }
    }

    if (qi < NQ) {
        float inv = 1.f / l;
        float* op = O + ((size_t)b * NQ + qi) * CC + h * DH;
#pragma unroll
        for (int d = 0; d < DH; d++) op[d] = acc[d] * inv;
    }
}

// ---------------------------------------------------------------------------
// fused residual + LayerNorm: v = a + r; optional store v; ln_out = LN(v)*g+b
// one 256-thread block per 256-element row.
// ---------------------------------------------------------------------------
__global__ __launch_bounds__(256) void resid_ln(const float* __restrict__ a,
                                                const float* __restrict__ r,
                                                const float* __restrict__ g,
                                                const float* __restrict__ be,
                                                float* __restrict__ sum_out,
                                                float* __restrict__ ln_out) {
    const int row = blockIdx.x;
    const int t = threadIdx.x;
    const size_t base = (size_t)row * CC;
    float v = a[base + t] + r[base + t];
    if (sum_out) sum_out[base + t] = v;

    __shared__ float red[4];
    float s = v;
#pragma unroll
    for (int o = 1; o < 64; o <<= 1) s += __shfl_xor(s, o, 64);
    if ((t & 63) == 0) red[t >> 6] = s;
    __syncthreads();
    float mean = (red[0] + red[1] + red[2] + red[3]) * (1.f / 256.f);
    __syncthreads();

    float d = v - mean;
    float sq = d * d;
#pragma unroll
    for (int o = 1; o < 64; o <<= 1) sq += __shfl_xor(sq, o, 64);
    if ((t & 63) == 0) red[t >> 6] = sq;
    __syncthreads();
    float var = (red[0] + red[1] + red[2] + red[3]) * (1.f / 256.f);

    ln_out[base + t] = d * rsqrtf(var + 1e-5f) * g[t] + be[t];
}

// ---------------------------------------------------------------------------
// deformable sampling: per (b,q) block; thread = (h, d).
// val: (B, NVAL, H, DH) fp32; off: (B,NQ,H,P,2); awl: (B,NQ,H,P) logits.
// ---------------------------------------------------------------------------
__global__ __launch_bounds__(256) void deform_sample(const float* __restrict__ val,
                                                     const float* __restrict__ off,
                                                     const float* __restrict__ awl,
                                                     const float* __restrict__ ref,
                                                     float* __restrict__ out) {
    const int bq = blockIdx.x;       // b*NQ + q
    const int b = bq / NQ;
    const int t = threadIdx.x;
    const int h = t >> 5, d = t & 31;

    const float rx = ref[(size_t)bq * 2 + 0];
    const float ry = ref[(size_t)bq * 2 + 1];

    const float* ap = awl + (size_t)bq * (HH * PP) + h * PP;
    float aw[PP];
    float mx = -1e30f;
#pragma unroll
    for (int p = 0; p < PP; p++) { aw[p] = ap[p]; mx = fmaxf(mx, aw[p]); }
    float se = 0.f;
#pragma unroll
    for (int p = 0; p < PP; p++) { aw[p] = __expf(aw[p] - mx); se += aw[p]; }
    const float inv = 1.f / se;

    const float* op = off + (size_t)bq * (HH * PP * 2) + h * (PP * 2);
    const float* vb = val + (size_t)b * NVAL * CC + h * DH + d;

    float acc = 0.f;
#pragma unroll
    for (int p = 0; p < PP; p++) {
        float x = (rx + op[p * 2 + 0] * (1.f / BEV)) * (float)BEV - 0.5f;
        float y = (ry + op[p * 2 + 1] * (1.f / BEV)) * (float)BEV - 0.5f;
        float xf = floorf(x), yf = floorf(y);
        float lx = x - xf, ly = y - yf;
        int x0 = (int)xf, y0 = (int)yf;
        float w = aw[p] * inv;

        float s = 0.f;
#pragma unroll
        for (int c = 0; c < 4; c++) {
            int xi = x0 + (c & 1);
            int yi = y0 + (c >> 1);
            float wx = (c & 1) ? lx : (1.f - lx);
            float wy = (c >> 1) ? ly : (1.f - ly);
            bool vld = (xi >= 0) && (xi < BEV) && (yi >= 0) && (yi < BEV);
            int xc = min(max(xi, 0), BEV - 1);
            int yc = min(max(yi, 0), BEV - 1);
            float gv = vb[(size_t)(yc * BEV + xc) * CC];
            s += vld ? (wx * wy * gv) : 0.f;
        }
        acc = fmaf(w, s, acc);
    }
    out[(size_t)bq * CC + t] = acc;
}

// ---------------------------------------------------------------------------
extern "C" void kernel_launch(void* const* d_in, const int* in_sizes, int n_in,
                              void* d_out, int out_size, void* d_ws, size_t ws_size,
                              hipStream_t stream) {
    const float* query   = (const float*)d_in[0];
    const float* value   = (const float*)d_in[1];
    const float* qpos    = (const float*)d_in[2];
    const float* ref2d   = (const float*)d_in[3];
    const float* in_w    = (const float*)d_in[4];
    const float* in_b    = (const float*)d_in[5];
    const float* outp_w  = (const float*)d_in[6];
    const float* outp_b  = (const float*)d_in[7];
    const float* off_w   = (const float*)d_in[8];
    const float* off_b   = (const float*)d_in[9];
    const float* aw_w    = (const float*)d_in[10];
    const float* aw_b    = (const float*)d_in[11];
    const float* vproj_w = (const float*)d_in[12];
    const float* vproj_b = (const float*)d_in[13];
    const float* oproj_w = (const float*)d_in[14];
    const float* oproj_b = (const float*)d_in[15];
    const float* ffn_w1  = (const float*)d_in[16];
    const float* ffn_b1  = (const float*)d_in[17];
    const float* ffn_w2  = (const float*)d_in[18];
    const float* ffn_b2  = (const float*)d_in[19];
    const float* ln1_g = (const float*)d_in[20], *ln1_b = (const float*)d_in[21];
    const float* ln2_g = (const float*)d_in[22], *ln2_b = (const float*)d_in[23];
    const float* ln3_g = (const float*)d_in[24], *ln3_b = (const float*)d_in[25];

    float* ws = (float*)d_ws;
    float* out = (float*)d_out;

    const int    M = BB * NQ;                 // 10000
    const size_t R = (size_t)M * CC;          // 2,560,000 floats

    // --- workspace layout (floats) ---
    // early region [0 .. 40.96M) is reused by VAL after the self-attn phase:
    float* QP   = ws;             // query+pos          (dead after q GEMM)
    float* Qb   = ws + 1 * R;
    float* Kb   = ws + 2 * R;
    float* Vb   = ws + 3 * R;
    float* SA   = ws + 4 * R;     // out_proj output    (dead after ln1)
    float* ATT  = ws + 5 * R;     // raw attn output    (dead after out_proj)
    float* VAL  = ws;             // (B*NVAL, 256) = 40.96M floats, written AFTER above die
    const size_t P0 = (size_t)BB * NVAL * CC; // 40,960,000
    float* X1   = ws + P0;
    float* XLN1 = ws + P0 + 1 * R;
    float* OFF  = ws + P0 + 2 * R;                       // 1.28M
    float* AWL  = ws + P0 + 2 * R + 1280000;             // 0.64M
    float* SAMP = ws + P0 + 2 * R + 1920000;
    float* CA   = ws + P0 + 3 * R + 1920000;
    float* XLN2 = ws + P0 + 4 * R + 1920000;
    float* FFNH = ws + P0 + 5 * R + 1920000;             // 5.12M
    float* FFNO = ws + P0 + 7 * R + 1920000;
    // total: 63.36M floats = 253.4 MB

    dim3 blk(256);
    const int mg = (M + BM - 1) / BM;   // 157

    // 1. qp = query + query_pos
    add_vec<<<dim3((int)(R / 4 + 255) / 256), blk, 0, stream>>>(query, qpos, QP, (int)(R / 4));
    // 2-4. q, k, v projections
    gemm_bias<false><<<dim3(CC / BN, mg), blk, 0, stream>>>(QP,    in_w,             in_b,           Qb, M, CC, CC);
    gemm_bias<false><<<dim3(CC / BN, mg), blk, 0, stream>>>(query, in_w + CC * CC,   in_b + CC,      Kb, M, CC, CC);
    gemm_bias<false><<<dim3(CC / BN, mg), blk, 0, stream>>>(query, in_w + 2 * CC * CC, in_b + 2 * CC, Vb, M, CC, CC);
    // 5. flash self-attention
    flash_attn<<<dim3((NQ + 255) / 256, BB * HH), blk, 0, stream>>>(Qb, Kb, Vb, ATT);
    // 6. out_proj
    gemm_bias<false><<<dim3(CC / BN, mg), blk, 0, stream>>>(ATT, outp_w, outp_b, SA, M, CC, CC);
    // 7. x1 = sa + query; xln1 = LN1(x1)
    resid_ln<<<dim3(M), blk, 0, stream>>>(SA, query, ln1_g, ln1_b, X1, XLN1);
    // 8. value projection (the big GEMM)
    gemm_bias<false><<<dim3(CC / BN, (BB * NVAL) / BM), blk, 0, stream>>>(value, vproj_w, vproj_b, VAL, BB * NVAL, CC, CC);
    // 9-10. offsets + attention-weight logits
    gemm_bias<false><<<dim3(128 / BN, mg), blk, 0, stream>>>(XLN1, off_w, off_b, OFF, M, 128, CC);
    gemm_bias<false><<<dim3(64 / BN, mg),  blk, 0, stream>>>(XLN1, aw_w,  aw_b,  AWL, M, 64,  CC);
    // 11. bilinear sampling + weighted sum
    deform_sample<<<dim3(M), blk, 0, stream>>>(VAL, OFF, AWL, ref2d, SAMP);
    // 12. output projection of deform attn
    gemm_bias<false><<<dim3(CC / BN, mg), blk, 0, stream>>>(SAMP, oproj_w, oproj_b, CA, M, CC, CC);
    // 13. x2 = ca + x1; xln2 = LN2(x2)
    resid_ln<<<dim3(M), blk, 0, stream>>>(CA, X1, ln2_g, ln2_b, nullptr, XLN2);
    // 14-15. FFN
    gemm_bias<true ><<<dim3(DFFN / BN, mg), blk, 0, stream>>>(XLN2, ffn_w1, ffn_b1, FFNH, M, DFFN, CC);
    gemm_bias<false><<<dim3(CC / BN, mg),   blk, 0, stream>>>(FFNH, ffn_w2, ffn_b2, FFNO, M, CC, DFFN);
    // 16. out = LN3(xln2 + ffn_out)
    resid_ln<<<dim3(M), blk, 0, stream>>>(FFNO, XLN2, ln3_g, ln3_b, nullptr, out);
}

// Round 2
// 2136.234 us; speedup vs baseline: 1.1365x; 1.1365x over previous
//
#include <hip/hip_runtime.h>

#define BB   4
#define NQ   2500
#define CC   256
#define HH   8
#define PP   8
#define DFFN 512
#define DH   32
#define BEV  200
#define NVAL (BEV * BEV)

#define KSPLIT 4
#define CHUNK  625          // NQ / KSPLIT
#define KT2    16

// ---------------------------------------------------------------------------
// elementwise add (float4)
// ---------------------------------------------------------------------------
__global__ __launch_bounds__(256) void add_vec(const float* __restrict__ a,
                                               const float* __restrict__ b,
                                               float* __restrict__ o, int n4) {
    int i = blockIdx.x * 256 + threadIdx.x;
    if (i < n4) {
        float4 av = reinterpret_cast<const float4*>(a)[i];
        float4 bv = reinterpret_cast<const float4*>(b)[i];
        float4 ov;
        ov.x = av.x + bv.x; ov.y = av.y + bv.y;
        ov.z = av.z + bv.z; ov.w = av.w + bv.w;
        reinterpret_cast<float4*>(o)[i] = ov;
    }
}

// ---------------------------------------------------------------------------
// generic tiled GEMM (64x64 tile):  C = A[M,K] @ W[N,K]^T + bias  (opt ReLU)
// ---------------------------------------------------------------------------
#define BM 64
#define BN 64
#define BK 16
template <bool RELU>
__global__ __launch_bounds__(256) void gemm_bias(const float* __restrict__ A,
                                                 const float* __restrict__ W,
                                                 const float* __restrict__ bias,
                                                 float* __restrict__ C,
                                                 int M, int N, int K) {
    __shared__ float As[BK][BM + 4];
    __shared__ float Ws[BK][BN + 4];
    const int m0 = blockIdx.y * BM;
    const int n0 = blockIdx.x * BN;
    const int t  = threadIdx.x;
    const int tx = t & 15;
    const int ty = t >> 4;
    const int lrow = t >> 2;
    const int lk   = (t & 3) << 2;

    float acc[4][4];
#pragma unroll
    for (int i = 0; i < 4; i++)
#pragma unroll
        for (int j = 0; j < 4; j++) acc[i][j] = 0.f;

    const bool aok = (m0 + lrow) < M;
    const float* Ap = A + (size_t)(m0 + lrow) * K + lk;
    const float* Wp = W + (size_t)(n0 + lrow) * K + lk;

    for (int k0 = 0; k0 < K; k0 += BK) {
        float4 av = make_float4(0.f, 0.f, 0.f, 0.f);
        if (aok) av = *reinterpret_cast<const float4*>(Ap + k0);
        float4 wv = *reinterpret_cast<const float4*>(Wp + k0);
        As[lk + 0][lrow] = av.x; As[lk + 1][lrow] = av.y;
        As[lk + 2][lrow] = av.z; As[lk + 3][lrow] = av.w;
        Ws[lk + 0][lrow] = wv.x; Ws[lk + 1][lrow] = wv.y;
        Ws[lk + 2][lrow] = wv.z; Ws[lk + 3][lrow] = wv.w;
        __syncthreads();
#pragma unroll
        for (int kk = 0; kk < BK; kk++) {
            float4 a4 = *reinterpret_cast<const float4*>(&As[kk][ty << 2]);
            float4 w4 = *reinterpret_cast<const float4*>(&Ws[kk][tx << 2]);
            float a[4] = {a4.x, a4.y, a4.z, a4.w};
            float w[4] = {w4.x, w4.y, w4.z, w4.w};
#pragma unroll
            for (int i = 0; i < 4; i++)
#pragma unroll
                for (int j = 0; j < 4; j++)
                    acc[i][j] = fmaf(a[i], w[j], acc[i][j]);
        }
        __syncthreads();
    }

    float4 b4 = *reinterpret_cast<const float4*>(bias + n0 + (tx << 2));
#pragma unroll
    for (int i = 0; i < 4; i++) {
        int row = m0 + (ty << 2) + i;
        if (row < M) {
            float4 o;
            o.x = acc[i][0] + b4.x; o.y = acc[i][1] + b4.y;
            o.z = acc[i][2] + b4.z; o.w = acc[i][3] + b4.w;
            if (RELU) {
                o.x = fmaxf(o.x, 0.f); o.y = fmaxf(o.y, 0.f);
                o.z = fmaxf(o.z, 0.f); o.w = fmaxf(o.w, 0.f);
            }
            *reinterpret_cast<float4*>(C + (size_t)row * N + n0 + (tx << 2)) = o;
        }
    }
}

// ---------------------------------------------------------------------------
// big-tile GEMM (128x128, 8x8 microtile) — only for grids with many blocks
// N must be a multiple of 128.
// ---------------------------------------------------------------------------
#define GM 128
#define GN 128
#define GK 16
__global__ __launch_bounds__(256) void gemm_bias128(const float* __restrict__ A,
                                                    const float* __restrict__ W,
                                                    const float* __restrict__ bias,
                                                    float* __restrict__ C,
                                                    int M, int N, int K) {
    __shared__ float As[GK][GM + 4];
    __shared__ float Ws[GK][GN + 4];
    const int m0 = blockIdx.y * GM;
    const int n0 = blockIdx.x * GN;
    const int t  = threadIdx.x;
    const int tx = t & 15;      // n
    const int ty = t >> 4;      // m
    const int lr = t >> 2;      // 0..63
    const int lk = (t & 3) << 2;

    float acc[8][8];
#pragma unroll
    for (int i = 0; i < 8; i++)
#pragma unroll
        for (int j = 0; j < 8; j++) acc[i][j] = 0.f;

    const bool aok0 = (m0 + lr) < M;
    const bool aok1 = (m0 + lr + 64) < M;
    const float* Ap0 = A + (size_t)(m0 + lr) * K + lk;
    const float* Ap1 = A + (size_t)(m0 + lr + 64) * K + lk;
    const float* Wp0 = W + (size_t)(n0 + lr) * K + lk;
    const float* Wp1 = W + (size_t)(n0 + lr + 64) * K + lk;

    for (int k0 = 0; k0 < K; k0 += GK) {
        float4 a0 = make_float4(0.f, 0.f, 0.f, 0.f);
        float4 a1 = make_float4(0.f, 0.f, 0.f, 0.f);
        if (aok0) a0 = *reinterpret_cast<const float4*>(Ap0 + k0);
        if (aok1) a1 = *reinterpret_cast<const float4*>(Ap1 + k0);
        float4 w0 = *reinterpret_cast<const float4*>(Wp0 + k0);
        float4 w1 = *reinterpret_cast<const float4*>(Wp1 + k0);
        As[lk + 0][lr] = a0.x; As[lk + 1][lr] = a0.y;
        As[lk + 2][lr] = a0.z; As[lk + 3][lr] = a0.w;
        As[lk + 0][lr + 64] = a1.x; As[lk + 1][lr + 64] = a1.y;
        As[lk + 2][lr + 64] = a1.z; As[lk + 3][lr + 64] = a1.w;
        Ws[lk + 0][lr] = w0.x; Ws[lk + 1][lr] = w0.y;
        Ws[lk + 2][lr] = w0.z; Ws[lk + 3][lr] = w0.w;
        Ws[lk + 0][lr + 64] = w1.x; Ws[lk + 1][lr + 64] = w1.y;
        Ws[lk + 2][lr + 64] = w1.z; Ws[lk + 3][lr + 64] = w1.w;
        __syncthreads();
#pragma unroll
        for (int kk = 0; kk < GK; kk++) {
            float4 aA = *reinterpret_cast<const float4*>(&As[kk][ty << 3]);
            float4 aB = *reinterpret_cast<const float4*>(&As[kk][(ty << 3) + 4]);
            float4 wA = *reinterpret_cast<const float4*>(&Ws[kk][tx << 3]);
            float4 wB = *reinterpret_cast<const float4*>(&Ws[kk][(tx << 3) + 4]);
            float a[8] = {aA.x, aA.y, aA.z, aA.w, aB.x, aB.y, aB.z, aB.w};
            float w[8] = {wA.x, wA.y, wA.z, wA.w, wB.x, wB.y, wB.z, wB.w};
#pragma unroll
            for (int i = 0; i < 8; i++)
#pragma unroll
                for (int j = 0; j < 8; j++)
                    acc[i][j] = fmaf(a[i], w[j], acc[i][j]);
        }
        __syncthreads();
    }

    float4 bA = *reinterpret_cast<const float4*>(bias + n0 + (tx << 3));
    float4 bB = *reinterpret_cast<const float4*>(bias + n0 + (tx << 3) + 4);
    float bb[8] = {bA.x, bA.y, bA.z, bA.w, bB.x, bB.y, bB.z, bB.w};
#pragma unroll
    for (int i = 0; i < 8; i++) {
        int row = m0 + (ty << 3) + i;
        if (row < M) {
            float4 oA, oB;
            oA.x = acc[i][0] + bb[0]; oA.y = acc[i][1] + bb[1];
            oA.z = acc[i][2] + bb[2]; oA.w = acc[i][3] + bb[3];
            oB.x = acc[i][4] + bb[4]; oB.y = acc[i][5] + bb[5];
            oB.z = acc[i][6] + bb[6]; oB.w = acc[i][7] + bb[7];
            float* cp = C + (size_t)row * N + n0 + (tx << 3);
            *reinterpret_cast<float4*>(cp)     = oA;
            *reinterpret_cast<float4*>(cp + 4) = oB;
        }
    }
}

// ---------------------------------------------------------------------------
// flash self-attention v2: K-split partials, no LDS — K/V rows are
// wave-uniform addresses (each lane owns a different q row), so loads are
// scalar-broadcast class served by L1/L2.
// grid: (ceil(NQ/256), B*H, KSPLIT)
// PART: [c][bh][q][32], ML: [c][bh][q][2]
// ---------------------------------------------------------------------------
__global__ __launch_bounds__(256, 4) void flash_part(const float* __restrict__ Q,
                                                     const float* __restrict__ Kb,
                                                     const float* __restrict__ Vb,
                                                     float* __restrict__ PART,
                                                     float* __restrict__ ML) {
    const int c  = blockIdx.z;
    const int bh = blockIdx.y;
    const int b = bh >> 3, h = bh & 7;
    const int t = threadIdx.x;
    const int qi = blockIdx.x * 256 + t;
    const int qrow = qi < NQ ? qi : NQ - 1;
    const float scale = 0.17677669529663687f;   // 1/sqrt(32)

    const float* qp = Q + ((size_t)b * NQ + qrow) * CC + h * DH;
    float qreg[DH];
#pragma unroll
    for (int d = 0; d < DH; d++) qreg[d] = qp[d] * scale;

    float m = -1e30f, l = 0.f;
    float acc[DH];
#pragma unroll
    for (int d = 0; d < DH; d++) acc[d] = 0.f;

    const size_t kvbase = (size_t)b * NQ * CC + (size_t)h * DH;
    const int ks = c * CHUNK;
    const int ke = ks + CHUNK;

    for (int k0 = ks; k0 < ke; k0 += KT2) {
        const int jn = (ke - k0) < KT2 ? (ke - k0) : KT2;
        float s[KT2];
        for (int j = 0; j < jn; j++) {
            const float4* kp = reinterpret_cast<const float4*>(Kb + kvbase + (size_t)(k0 + j) * CC);
            float s0 = 0.f, s1 = 0.f;
#pragma unroll
            for (int d4 = 0; d4 < 8; d4 += 2) {
                float4 k4a = kp[d4], k4b = kp[d4 + 1];
                s0 = fmaf(qreg[d4 * 4 + 0], k4a.x, s0);
                s0 = fmaf(qreg[d4 * 4 + 1], k4a.y, s0);
                s0 = fmaf(qreg[d4 * 4 + 2], k4a.z, s0);
                s0 = fmaf(qreg[d4 * 4 + 3], k4a.w, s0);
                s1 = fmaf(qreg[d4 * 4 + 4], k4b.x, s1);
                s1 = fmaf(qreg[d4 * 4 + 5], k4b.y, s1);
                s1 = fmaf(qreg[d4 * 4 + 6], k4b.z, s1);
                s1 = fmaf(qreg[d4 * 4 + 7], k4b.w, s1);
            }
            s[j] = s0 + s1;
        }
        float tm = m;
        for (int j = 0; j < jn; j++) tm = fmaxf(tm, s[j]);
        float cor = __expf(m - tm);
        m = tm;
        l *= cor;
#pragma unroll
        for (int d = 0; d < DH; d++) acc[d] *= cor;

        for (int j = 0; j < jn; j++) {
            float p = __expf(s[j] - m);
            l += p;
            const float4* vp = reinterpret_cast<const float4*>(Vb + kvbase + (size_t)(k0 + j) * CC);
#pragma unroll
            for (int d4 = 0; d4 < 8; d4++) {
                float4 v4 = vp[d4];
                acc[d4 * 4 + 0] = fmaf(p, v4.x, acc[d4 * 4 + 0]);
                acc[d4 * 4 + 1] = fmaf(p, v4.y, acc[d4 * 4 + 1]);
                acc[d4 * 4 + 2] = fmaf(p, v4.z, acc[d4 * 4 + 2]);
                acc[d4 * 4 + 3] = fmaf(p, v4.w, acc[d4 * 4 + 3]);
            }
        }
    }

    if (qi < NQ) {
        float* pp = PART + ((size_t)(c * (BB * HH) + bh) * NQ + qi) * DH;
#pragma unroll
        for (int d4 = 0; d4 < 8; d4++) {
            float4 o;
            o.x = acc[d4 * 4 + 0]; o.y = acc[d4 * 4 + 1];
            o.z = acc[d4 * 4 + 2]; o.w = acc[d4 * 4 + 3];
            reinterpret_cast<float4*>(pp)[d4] = o;
        }
        float* mp = ML + ((size_t)(c * (BB * HH) + bh) * NQ + qi) * 2;
        mp[0] = m; mp[1] = l;
    }
}

// combine KSPLIT partials -> O (B, NQ, H*DH)
__global__ __launch_bounds__(256) void flash_combine(const float* __restrict__ PART,
                                                     const float* __restrict__ ML,
                                                     float* __restrict__ O) {
    const int o = blockIdx.x * 256 + threadIdx.x;   // < B*NQ*CC
    const int bq = o >> 8;
    const int hd = o & 255;
    const int h = hd >> 5, d = hd & 31;
    const int b = bq / NQ, q = bq - b * NQ;
    const int bh = b * HH + h;

    float mv[KSPLIT], lv[KSPLIT];
    float M = -1e30f;
#pragma unroll
    for (int c = 0; c < KSPLIT; c++) {
        const float* mp = ML + ((size_t)(c * (BB * HH) + bh) * NQ + q) * 2;
        mv[c] = mp[0]; lv[c] = mp[1];
        M = fmaxf(M, mv[c]);
    }
    float L = 0.f, S = 0.f;
#pragma unroll
    for (int c = 0; c < KSPLIT; c++) {
        float w = __expf(mv[c] - M);
        L += w * lv[c];
        S += w * PART[((size_t)(c * (BB * HH) + bh) * NQ + q) * DH + d];
    }
    O[o] = S / L;
}

// ---------------------------------------------------------------------------
// fused residual + LayerNorm
// ---------------------------------------------------------------------------
__global__ __launch_bounds__(256) void resid_ln(const float* __restrict__ a,
                                                const float* __restrict__ r,
                                                const float* __restrict__ g,
                                                const float* __restrict__ be,
                                                float* __restrict__ sum_out,
                                                float* __restrict__ ln_out) {
    const int row = blockIdx.x;
    const int t = threadIdx.x;
    const size_t base = (size_t)row * CC;
    float v = a[base + t] + r[base + t];
    if (sum_out) sum_out[base + t] = v;

    __shared__ float red[4];
    float s = v;
#pragma unroll
    for (int o = 1; o < 64; o <<= 1) s += __shfl_xor(s, o, 64);
    if ((t & 63) == 0) red[t >> 6] = s;
    __syncthreads();
    float mean = (red[0] + red[1] + red[2] + red[3]) * (1.f / 256.f);
    __syncthreads();

    float d = v - mean;
    float sq = d * d;
#pragma unroll
    for (int o = 1; o < 64; o <<= 1) sq += __shfl_xor(sq, o, 64);
    if ((t & 63) == 0) red[t >> 6] = sq;
    __syncthreads();
    float var = (red[0] + red[1] + red[2] + red[3]) * (1.f / 256.f);

    ln_out[base + t] = d * rsqrtf(var + 1e-5f) * g[t] + be[t];
}

// ---------------------------------------------------------------------------
// deformable sampling
// ---------------------------------------------------------------------------
__global__ __launch_bounds__(256) void deform_sample(const float* __restrict__ val,
                                                     const float* __restrict__ off,
                                                     const float* __restrict__ awl,
                                                     const float* __restrict__ ref,
                                                     float* __restrict__ out) {
    const int bq = blockIdx.x;
    const int b = bq / NQ;
    const int t = threadIdx.x;
    const int h = t >> 5, d = t & 31;

    const float rx = ref[(size_t)bq * 2 + 0];
    const float ry = ref[(size_t)bq * 2 + 1];

    const float* ap = awl + (size_t)bq * (HH * PP) + h * PP;
    float aw[PP];
    float mx = -1e30f;
#pragma unroll
    for (int p = 0; p < PP; p++) { aw[p] = ap[p]; mx = fmaxf(mx, aw[p]); }
    float se = 0.f;
#pragma unroll
    for (int p = 0; p < PP; p++) { aw[p] = __expf(aw[p] - mx); se += aw[p]; }
    const float inv = 1.f / se;

    const float* op = off + (size_t)bq * (HH * PP * 2) + h * (PP * 2);
    const float* vb = val + (size_t)b * NVAL * CC + h * DH + d;

    float acc = 0.f;
#pragma unroll
    for (int p = 0; p < PP; p++) {
        float x = (rx + op[p * 2 + 0] * (1.f / BEV)) * (float)BEV - 0.5f;
        float y = (ry + op[p * 2 + 1] * (1.f / BEV)) * (float)BEV - 0.5f;
        float xf = floorf(x), yf = floorf(y);
        float lx = x - xf, ly = y - yf;
        int x0 = (int)xf, y0 = (int)yf;
        float w = aw[p] * inv;

        float s = 0.f;
#pragma unroll
        for (int c = 0; c < 4; c++) {
            int xi = x0 + (c & 1);
            int yi = y0 + (c >> 1);
            float wx = (c & 1) ? lx : (1.f - lx);
            float wy = (c >> 1) ? ly : (1.f - ly);
            bool vld = (xi >= 0) && (xi < BEV) && (yi >= 0) && (yi < BEV);
            int xc = min(max(xi, 0), BEV - 1);
            int yc = min(max(yi, 0), BEV - 1);
            float gv = vb[(size_t)(yc * BEV + xc) * CC];
            s += vld ? (wx * wy * gv) : 0.f;
        }
        acc = fmaf(w, s, acc);
    }
    out[(size_t)bq * CC + t] = acc;
}

// ---------------------------------------------------------------------------
extern "C" void kernel_launch(void* const* d_in, const int* in_sizes, int n_in,
                              void* d_out, int out_size, void* d_ws, size_t ws_size,
                              hipStream_t stream) {
    const float* query   = (const float*)d_in[0];
    const float* value   = (const float*)d_in[1];
    const float* qpos    = (const float*)d_in[2];
    const float* ref2d   = (const float*)d_in[3];
    const float* in_w    = (const float*)d_in[4];
    const float* in_b    = (const float*)d_in[5];
    const float* outp_w  = (const float*)d_in[6];
    const float* outp_b  = (const float*)d_in[7];
    const float* off_w   = (const float*)d_in[8];
    const float* off_b   = (const float*)d_in[9];
    const float* aw_w    = (const float*)d_in[10];
    const float* aw_b    = (const float*)d_in[11];
    const float* vproj_w = (const float*)d_in[12];
    const float* vproj_b = (const float*)d_in[13];
    const float* oproj_w = (const float*)d_in[14];
    const float* oproj_b = (const float*)d_in[15];
    const float* ffn_w1  = (const float*)d_in[16];
    const float* ffn_b1  = (const float*)d_in[17];
    const float* ffn_w2  = (const float*)d_in[18];
    const float* ffn_b2  = (const float*)d_in[19];
    const float* ln1_g = (const float*)d_in[20], *ln1_b = (const float*)d_in[21];
    const float* ln2_g = (const float*)d_in[22], *ln2_b = (const float*)d_in[23];
    const float* ln3_g = (const float*)d_in[24], *ln3_b = (const float*)d_in[25];

    float* ws = (float*)d_ws;
    float* out = (float*)d_out;

    const int    M = BB * NQ;                 // 10000
    const size_t R = (size_t)M * CC;          // 2,560,000 floats

    // --- workspace layout (floats) ---
    float* QP   = ws;
    float* Qb   = ws + 1 * R;
    float* Kb   = ws + 2 * R;
    float* Vb   = ws + 3 * R;
    float* SA   = ws + 4 * R;
    float* ATT  = ws + 5 * R;
    float* PART = ws + 6 * R;                 // 10.24M floats (dies before VAL)
    float* ML   = ws + 6 * R + (size_t)KSPLIT * BB * HH * NQ * DH;   // 0.64M
    float* VAL  = ws;                          // 40.96M floats, written later
    const size_t P0 = (size_t)BB * NVAL * CC;  // 40,960,000
    float* X1   = ws + P0;
    float* XLN1 = ws + P0 + 1 * R;
    float* OFF  = ws + P0 + 2 * R;
    float* AWL  = ws + P0 + 2 * R + 1280000;
    float* SAMP = ws + P0 + 2 * R + 1920000;
    float* CA   = ws + P0 + 3 * R + 1920000;
    float* XLN2 = ws + P0 + 4 * R + 1920000;
    float* FFNH = ws + P0 + 5 * R + 1920000;
    float* FFNO = ws + P0 + 7 * R + 1920000;

    dim3 blk(256);
    const int mg  = (M + BM - 1) / BM;    // 157
    const int mg1 = (M + GM - 1) / GM;    // 79

    // 1. qp = query + query_pos
    add_vec<<<dim3((int)(R / 4 + 255) / 256), blk, 0, stream>>>(query, qpos, QP, (int)(R / 4));
    // 2-4. q, k, v projections
    gemm_bias<false><<<dim3(CC / BN, mg), blk, 0, stream>>>(QP,    in_w,               in_b,           Qb, M, CC, CC);
    gemm_bias<false><<<dim3(CC / BN, mg), blk, 0, stream>>>(query, in_w + CC * CC,     in_b + CC,      Kb, M, CC, CC);
    gemm_bias<false><<<dim3(CC / BN, mg), blk, 0, stream>>>(query, in_w + 2 * CC * CC, in_b + 2 * CC,  Vb, M, CC, CC);
    // 5. flash self-attention (K-split partials + combine)
    flash_part<<<dim3((NQ + 255) / 256, BB * HH, KSPLIT), blk, 0, stream>>>(Qb, Kb, Vb, PART, ML);
    flash_combine<<<dim3((int)(R / 256)), blk, 0, stream>>>(PART, ML, ATT);
    // 6. out_proj
    gemm_bias<false><<<dim3(CC / BN, mg), blk, 0, stream>>>(ATT, outp_w, outp_b, SA, M, CC, CC);
    // 7. x1 = sa + query; xln1 = LN1(x1)
    resid_ln<<<dim3(M), blk, 0, stream>>>(SA, query, ln1_g, ln1_b, X1, XLN1);
    // 8. value projection (the big GEMM) — 128x128 tile, 2500 blocks
    gemm_bias128<<<dim3(CC / GN, (BB * NVAL) / GM), blk, 0, stream>>>(value, vproj_w, vproj_b, VAL, BB * NVAL, CC, CC);
    // 9-10. offsets + attention-weight logits
    gemm_bias<false><<<dim3(128 / BN, mg), blk, 0, stream>>>(XLN1, off_w, off_b, OFF, M, 128, CC);
    gemm_bias<false><<<dim3(64 / BN, mg),  blk, 0, stream>>>(XLN1, aw_w,  aw_b,  AWL, M, 64,  CC);
    // 11. bilinear sampling + weighted sum
    deform_sample<<<dim3(M), blk, 0, stream>>>(VAL, OFF, AWL, ref2d, SAMP);
    // 12. output projection of deform attn
    gemm_bias<false><<<dim3(CC / BN, mg), blk, 0, stream>>>(SAMP, oproj_w, oproj_b, CA, M, CC, CC);
    // 13. x2 = ca + x1; xln2 = LN2(x2)
    resid_ln<<<dim3(M), blk, 0, stream>>>(CA, X1, ln2_g, ln2_b, nullptr, XLN2);
    // 14-15. FFN
    gemm_bias<true ><<<dim3(DFFN / BN, mg), blk, 0, stream>>>(XLN2, ffn_w1, ffn_b1, FFNH, M, DFFN, CC);
    gemm_bias<false><<<dim3(CC / BN, mg),   blk, 0, stream>>>(FFNH, ffn_w2, ffn_b2, FFNO, M, CC, DFFN);
    // 16. out = LN3(xln2 + ffn_out)
    resid_ln<<<dim3(M), blk, 0, stream>>>(FFNO, XLN2, ln3_g, ln3_b, nullptr, out);
}

// Round 3
// 1387.111 us; speedup vs baseline: 1.7503x; 1.5401x over previous
//
#include <hip/hip_runtime.h>

#define BB   4
#define NQ   2500
#define CC   256
#define HH   8
#define PP   8
#define DFFN 512
#define DH   32
#define BEV  200
#define NVAL (BEV * BEV)

// ---------------------------------------------------------------------------
// elementwise add (float4)
// ---------------------------------------------------------------------------
__global__ __launch_bounds__(256) void add_vec(const float* __restrict__ a,
                                               const float* __restrict__ b,
                                               float* __restrict__ o, int n4) {
    int i = blockIdx.x * 256 + threadIdx.x;
    if (i < n4) {
        float4 av = reinterpret_cast<const float4*>(a)[i];
        float4 bv = reinterpret_cast<const float4*>(b)[i];
        float4 ov;
        ov.x = av.x + bv.x; ov.y = av.y + bv.y;
        ov.z = av.z + bv.z; ov.w = av.w + bv.w;
        reinterpret_cast<float4*>(o)[i] = ov;
    }
}

// ---------------------------------------------------------------------------
// generic tiled GEMM (64x64 tile):  C = A[M,K] @ W[N,K]^T + bias  (opt ReLU)
// ---------------------------------------------------------------------------
#define BM 64
#define BN 64
#define BK 16
template <bool RELU>
__global__ __launch_bounds__(256) void gemm_bias(const float* __restrict__ A,
                                                 const float* __restrict__ W,
                                                 const float* __restrict__ bias,
                                                 float* __restrict__ C,
                                                 int M, int N, int K) {
    __shared__ float As[BK][BM + 4];
    __shared__ float Ws[BK][BN + 4];
    const int m0 = blockIdx.y * BM;
    const int n0 = blockIdx.x * BN;
    const int t  = threadIdx.x;
    const int tx = t & 15;
    const int ty = t >> 4;
    const int lrow = t >> 2;
    const int lk   = (t & 3) << 2;

    float acc[4][4];
#pragma unroll
    for (int i = 0; i < 4; i++)
#pragma unroll
        for (int j = 0; j < 4; j++) acc[i][j] = 0.f;

    const bool aok = (m0 + lrow) < M;
    const float* Ap = A + (size_t)(m0 + lrow) * K + lk;
    const float* Wp = W + (size_t)(n0 + lrow) * K + lk;

    for (int k0 = 0; k0 < K; k0 += BK) {
        float4 av = make_float4(0.f, 0.f, 0.f, 0.f);
        if (aok) av = *reinterpret_cast<const float4*>(Ap + k0);
        float4 wv = *reinterpret_cast<const float4*>(Wp + k0);
        As[lk + 0][lrow] = av.x; As[lk + 1][lrow] = av.y;
        As[lk + 2][lrow] = av.z; As[lk + 3][lrow] = av.w;
        Ws[lk + 0][lrow] = wv.x; Ws[lk + 1][lrow] = wv.y;
        Ws[lk + 2][lrow] = wv.z; Ws[lk + 3][lrow] = wv.w;
        __syncthreads();
#pragma unroll
        for (int kk = 0; kk < BK; kk++) {
            float4 a4 = *reinterpret_cast<const float4*>(&As[kk][ty << 2]);
            float4 w4 = *reinterpret_cast<const float4*>(&Ws[kk][tx << 2]);
            float a[4] = {a4.x, a4.y, a4.z, a4.w};
            float w[4] = {w4.x, w4.y, w4.z, w4.w};
#pragma unroll
            for (int i = 0; i < 4; i++)
#pragma unroll
                for (int j = 0; j < 4; j++)
                    acc[i][j] = fmaf(a[i], w[j], acc[i][j]);
        }
        __syncthreads();
    }

    float4 b4 = *reinterpret_cast<const float4*>(bias + n0 + (tx << 2));
#pragma unroll
    for (int i = 0; i < 4; i++) {
        int row = m0 + (ty << 2) + i;
        if (row < M) {
            float4 o;
            o.x = acc[i][0] + b4.x; o.y = acc[i][1] + b4.y;
            o.z = acc[i][2] + b4.z; o.w = acc[i][3] + b4.w;
            if (RELU) {
                o.x = fmaxf(o.x, 0.f); o.y = fmaxf(o.y, 0.f);
                o.z = fmaxf(o.z, 0.f); o.w = fmaxf(o.w, 0.f);
            }
            *reinterpret_cast<float4*>(C + (size_t)row * N + n0 + (tx << 2)) = o;
        }
    }
}

// ---------------------------------------------------------------------------
// big-tile GEMM (128x128, 8x8 microtile) — for grids with many blocks
// ---------------------------------------------------------------------------
#define GM 128
#define GN 128
#define GK 16
__global__ __launch_bounds__(256) void gemm_bias128(const float* __restrict__ A,
                                                    const float* __restrict__ W,
                                                    const float* __restrict__ bias,
                                                    float* __restrict__ C,
                                                    int M, int N, int K) {
    __shared__ float As[GK][GM + 4];
    __shared__ float Ws[GK][GN + 4];
    const int m0 = blockIdx.y * GM;
    const int n0 = blockIdx.x * GN;
    const int t  = threadIdx.x;
    const int tx = t & 15;
    const int ty = t >> 4;
    const int lr = t >> 2;
    const int lk = (t & 3) << 2;

    float acc[8][8];
#pragma unroll
    for (int i = 0; i < 8; i++)
#pragma unroll
        for (int j = 0; j < 8; j++) acc[i][j] = 0.f;

    const bool aok0 = (m0 + lr) < M;
    const bool aok1 = (m0 + lr + 64) < M;
    const float* Ap0 = A + (size_t)(m0 + lr) * K + lk;
    const float* Ap1 = A + (size_t)(m0 + lr + 64) * K + lk;
    const float* Wp0 = W + (size_t)(n0 + lr) * K + lk;
    const float* Wp1 = W + (size_t)(n0 + lr + 64) * K + lk;

    for (int k0 = 0; k0 < K; k0 += GK) {
        float4 a0 = make_float4(0.f, 0.f, 0.f, 0.f);
        float4 a1 = make_float4(0.f, 0.f, 0.f, 0.f);
        if (aok0) a0 = *reinterpret_cast<const float4*>(Ap0 + k0);
        if (aok1) a1 = *reinterpret_cast<const float4*>(Ap1 + k0);
        float4 w0 = *reinterpret_cast<const float4*>(Wp0 + k0);
        float4 w1 = *reinterpret_cast<const float4*>(Wp1 + k0);
        As[lk + 0][lr] = a0.x; As[lk + 1][lr] = a0.y;
        As[lk + 2][lr] = a0.z; As[lk + 3][lr] = a0.w;
        As[lk + 0][lr + 64] = a1.x; As[lk + 1][lr + 64] = a1.y;
        As[lk + 2][lr + 64] = a1.z; As[lk + 3][lr + 64] = a1.w;
        Ws[lk + 0][lr] = w0.x; Ws[lk + 1][lr] = w0.y;
        Ws[lk + 2][lr] = w0.z; Ws[lk + 3][lr] = w0.w;
        Ws[lk + 0][lr + 64] = w1.x; Ws[lk + 1][lr + 64] = w1.y;
        Ws[lk + 2][lr + 64] = w1.z; Ws[lk + 3][lr + 64] = w1.w;
        __syncthreads();
#pragma unroll
        for (int kk = 0; kk < GK; kk++) {
            float4 aA = *reinterpret_cast<const float4*>(&As[kk][ty << 3]);
            float4 aB = *reinterpret_cast<const float4*>(&As[kk][(ty << 3) + 4]);
            float4 wA = *reinterpret_cast<const float4*>(&Ws[kk][tx << 3]);
            float4 wB = *reinterpret_cast<const float4*>(&Ws[kk][(tx << 3) + 4]);
            float a[8] = {aA.x, aA.y, aA.z, aA.w, aB.x, aB.y, aB.z, aB.w};
            float w[8] = {wA.x, wA.y, wA.z, wA.w, wB.x, wB.y, wB.z, wB.w};
#pragma unroll
            for (int i = 0; i < 8; i++)
#pragma unroll
                for (int j = 0; j < 8; j++)
                    acc[i][j] = fmaf(a[i], w[j], acc[i][j]);
        }
        __syncthreads();
    }

    float4 bA = *reinterpret_cast<const float4*>(bias + n0 + (tx << 3));
    float4 bB = *reinterpret_cast<const float4*>(bias + n0 + (tx << 3) + 4);
    float bb[8] = {bA.x, bA.y, bA.z, bA.w, bB.x, bB.y, bB.z, bB.w};
#pragma unroll
    for (int i = 0; i < 8; i++) {
        int row = m0 + (ty << 3) + i;
        if (row < M) {
            float4 oA, oB;
            oA.x = acc[i][0] + bb[0]; oA.y = acc[i][1] + bb[1];
            oA.z = acc[i][2] + bb[2]; oA.w = acc[i][3] + bb[3];
            oB.x = acc[i][4] + bb[4]; oB.y = acc[i][5] + bb[5];
            oB.z = acc[i][6] + bb[6]; oB.w = acc[i][7] + bb[7];
            float* cp = C + (size_t)row * N + n0 + (tx << 3);
            *reinterpret_cast<float4*>(cp)     = oA;
            *reinterpret_cast<float4*>(cp + 4) = oB;
        }
    }
}

// ---------------------------------------------------------------------------
// flash self-attention v3: 64x64 tile GEMM through LDS, online softmax.
// grid: ((NQ+63)/64, B*H), 256 threads.
// S-phase: 4x4 microtile (ty=q-rows, tx=key-cols); P via LDS (row-major,
// reads broadcast over tx); PV: O-microtile 4 rows x 2 d-cols.
// K/V tiles reg-prefetched (issue early, ds_write after barrier).
// ---------------------------------------------------------------------------
#define QT 64
#define NT ((NQ + QT - 1) / QT)   // 40
__global__ __launch_bounds__(256, 2) void flash_tile(const float* __restrict__ Q,
                                                     const float* __restrict__ Kb,
                                                     const float* __restrict__ Vb,
                                                     float* __restrict__ O) {
    __shared__ float Qs[DH][QT + 4];   // [32][68] k-major, scaled
    __shared__ float Ks[DH][QT + 4];   // [32][68] k-major
    __shared__ float Vs[QT][DH + 4];   // [64][36] row-major
    __shared__ float Ps[QT][QT + 4];   // [64][68] row-major

    const int bh = blockIdx.y;
    const int b = bh >> 3, h = bh & 7;
    const int t = threadIdx.x;
    const int tx = t & 15;
    const int ty = t >> 4;
    const int lrow = t >> 2;          // 0..63
    const int lk8  = (t & 3) << 3;    // 0,8,16,24
    const int q0 = blockIdx.x * QT;
    const float scale = 0.17677669529663687f;   // 1/sqrt(32)

    // ---- load Q tile (scaled) into LDS ----
    {
        int qr = q0 + lrow; if (qr >= NQ) qr = NQ - 1;
        const float* qp = Q + ((size_t)b * NQ + qr) * CC + h * DH + lk8;
        float4 qa = *reinterpret_cast<const float4*>(qp);
        float4 qb2 = *reinterpret_cast<const float4*>(qp + 4);
        Qs[lk8 + 0][lrow] = qa.x * scale;  Qs[lk8 + 1][lrow] = qa.y * scale;
        Qs[lk8 + 2][lrow] = qa.z * scale;  Qs[lk8 + 3][lrow] = qa.w * scale;
        Qs[lk8 + 4][lrow] = qb2.x * scale; Qs[lk8 + 5][lrow] = qb2.y * scale;
        Qs[lk8 + 6][lrow] = qb2.z * scale; Qs[lk8 + 7][lrow] = qb2.w * scale;
    }

    const size_t kvbase = (size_t)b * NQ * CC + (size_t)h * DH + lk8;

    // prefetch K/V tile 0 into registers
    float4 pk0, pk1, pv0, pv1;
    {
        int kr = lrow;   // tile 0
        const float* kp = Kb + kvbase + (size_t)kr * CC;
        const float* vp = Vb + kvbase + (size_t)kr * CC;
        pk0 = *reinterpret_cast<const float4*>(kp);
        pk1 = *reinterpret_cast<const float4*>(kp + 4);
        pv0 = *reinterpret_cast<const float4*>(vp);
        pv1 = *reinterpret_cast<const float4*>(vp + 4);
    }

    float m[4], l[4], o[4][2];
#pragma unroll
    for (int i = 0; i < 4; i++) {
        m[i] = -1e30f; l[i] = 0.f; o[i][0] = 0.f; o[i][1] = 0.f;
    }

    for (int kt = 0; kt < NT; kt++) {
        __syncthreads();   // WAR: prev iter done reading Ks/Vs/Ps

        // regs -> LDS
        Ks[lk8 + 0][lrow] = pk0.x; Ks[lk8 + 1][lrow] = pk0.y;
        Ks[lk8 + 2][lrow] = pk0.z; Ks[lk8 + 3][lrow] = pk0.w;
        Ks[lk8 + 4][lrow] = pk1.x; Ks[lk8 + 5][lrow] = pk1.y;
        Ks[lk8 + 6][lrow] = pk1.z; Ks[lk8 + 7][lrow] = pk1.w;
        *reinterpret_cast<float4*>(&Vs[lrow][lk8])     = pv0;
        *reinterpret_cast<float4*>(&Vs[lrow][lk8 + 4]) = pv1;
        __syncthreads();   // stores visible

        // issue next tile's loads early — complete under S/softmax/PV
        if (kt + 1 < NT) {
            int kr = (kt + 1) * QT + lrow; if (kr >= NQ) kr = NQ - 1;
            const float* kp = Kb + kvbase + (size_t)kr * CC;
            const float* vp = Vb + kvbase + (size_t)kr * CC;
            pk0 = *reinterpret_cast<const float4*>(kp);
            pk1 = *reinterpret_cast<const float4*>(kp + 4);
            pv0 = *reinterpret_cast<const float4*>(vp);
            pv1 = *reinterpret_cast<const float4*>(vp + 4);
        }

        // ---- S = Qtile @ Ktile^T ----
        float s[4][4];
#pragma unroll
        for (int i = 0; i < 4; i++)
#pragma unroll
            for (int j = 0; j < 4; j++) s[i][j] = 0.f;
#pragma unroll
        for (int kk = 0; kk < DH; kk++) {
            float4 a4 = *reinterpret_cast<const float4*>(&Qs[kk][ty << 2]);
            float4 k4 = *reinterpret_cast<const float4*>(&Ks[kk][tx << 2]);
            float a[4] = {a4.x, a4.y, a4.z, a4.w};
            float kv[4] = {k4.x, k4.y, k4.z, k4.w};
#pragma unroll
            for (int i = 0; i < 4; i++)
#pragma unroll
                for (int j = 0; j < 4; j++)
                    s[i][j] = fmaf(a[i], kv[j], s[i][j]);
        }

        // mask invalid keys (last tile only)
        if (kt == NT - 1) {
            const int rem = NQ - kt * QT;   // 4
#pragma unroll
            for (int j = 0; j < 4; j++)
                if (tx * 4 + j >= rem) {
#pragma unroll
                    for (int i = 0; i < 4; i++) s[i][j] = -1e30f;
                }
        }

        // ---- online softmax (row reduce over 16 tx lanes) ----
#pragma unroll
        for (int i = 0; i < 4; i++) {
            float rm = fmaxf(fmaxf(s[i][0], s[i][1]), fmaxf(s[i][2], s[i][3]));
            rm = fmaxf(rm, __shfl_xor(rm, 1));
            rm = fmaxf(rm, __shfl_xor(rm, 2));
            rm = fmaxf(rm, __shfl_xor(rm, 4));
            rm = fmaxf(rm, __shfl_xor(rm, 8));
            float mn = fmaxf(m[i], rm);
            float cor = __expf(m[i] - mn);
            m[i] = mn;
            float p0 = __expf(s[i][0] - mn);
            float p1 = __expf(s[i][1] - mn);
            float p2 = __expf(s[i][2] - mn);
            float p3 = __expf(s[i][3] - mn);
            float rs = p0 + p1 + p2 + p3;
            rs += __shfl_xor(rs, 1);
            rs += __shfl_xor(rs, 2);
            rs += __shfl_xor(rs, 4);
            rs += __shfl_xor(rs, 8);
            l[i] = l[i] * cor + rs;
            o[i][0] *= cor; o[i][1] *= cor;
            float4 pw = make_float4(p0, p1, p2, p3);
            *reinterpret_cast<float4*>(&Ps[(ty << 2) + i][tx << 2]) = pw;
        }
        __syncthreads();   // Ps visible

        // ---- O += P @ Vtile ----
#pragma unroll
        for (int kk0 = 0; kk0 < QT; kk0 += 4) {
            float4 p4[4];
#pragma unroll
            for (int i = 0; i < 4; i++)
                p4[i] = *reinterpret_cast<const float4*>(&Ps[(ty << 2) + i][kk0]);
            float2 v4[4];
#pragma unroll
            for (int r = 0; r < 4; r++)
                v4[r] = *reinterpret_cast<const float2*>(&Vs[kk0 + r][tx << 1]);
#pragma unroll
            for (int i = 0; i < 4; i++) {
                float pr[4] = {p4[i].x, p4[i].y, p4[i].z, p4[i].w};
#pragma unroll
                for (int r = 0; r < 4; r++) {
                    o[i][0] = fmaf(pr[r], v4[r].x, o[i][0]);
                    o[i][1] = fmaf(pr[r], v4[r].y, o[i][1]);
                }
            }
        }
    }

    // ---- store ----
#pragma unroll
    for (int i = 0; i < 4; i++) {
        int row = q0 + (ty << 2) + i;
        if (row < NQ) {
            float inv = 1.f / l[i];
            float2 st;
            st.x = o[i][0] * inv; st.y = o[i][1] * inv;
            *reinterpret_cast<float2*>(O + ((size_t)b * NQ + row) * CC + h * DH + (tx << 1)) = st;
        }
    }
}

// ---------------------------------------------------------------------------
// fused residual + LayerNorm
// ---------------------------------------------------------------------------
__global__ __launch_bounds__(256) void resid_ln(const float* __restrict__ a,
                                                const float* __restrict__ r,
                                                const float* __restrict__ g,
                                                const float* __restrict__ be,
                                                float* __restrict__ sum_out,
                                                float* __restrict__ ln_out) {
    const int row = blockIdx.x;
    const int t = threadIdx.x;
    const size_t base = (size_t)row * CC;
    float v = a[base + t] + r[base + t];
    if (sum_out) sum_out[base + t] = v;

    __shared__ float red[4];
    float s = v;
#pragma unroll
    for (int o = 1; o < 64; o <<= 1) s += __shfl_xor(s, o, 64);
    if ((t & 63) == 0) red[t >> 6] = s;
    __syncthreads();
    float mean = (red[0] + red[1] + red[2] + red[3]) * (1.f / 256.f);
    __syncthreads();

    float d = v - mean;
    float sq = d * d;
#pragma unroll
    for (int o = 1; o < 64; o <<= 1) sq += __shfl_xor(sq, o, 64);
    if ((t & 63) == 0) red[t >> 6] = sq;
    __syncthreads();
    float var = (red[0] + red[1] + red[2] + red[3]) * (1.f / 256.f);

    ln_out[base + t] = d * rsqrtf(var + 1e-5f) * g[t] + be[t];
}

// ---------------------------------------------------------------------------
// deformable sampling
// ---------------------------------------------------------------------------
__global__ __launch_bounds__(256) void deform_sample(const float* __restrict__ val,
                                                     const float* __restrict__ off,
                                                     const float* __restrict__ awl,
                                                     const float* __restrict__ ref,
                                                     float* __restrict__ out) {
    const int bq = blockIdx.x;
    const int b = bq / NQ;
    const int t = threadIdx.x;
    const int h = t >> 5, d = t & 31;

    const float rx = ref[(size_t)bq * 2 + 0];
    const float ry = ref[(size_t)bq * 2 + 1];

    const float* ap = awl + (size_t)bq * (HH * PP) + h * PP;
    float aw[PP];
    float mx = -1e30f;
#pragma unroll
    for (int p = 0; p < PP; p++) { aw[p] = ap[p]; mx = fmaxf(mx, aw[p]); }
    float se = 0.f;
#pragma unroll
    for (int p = 0; p < PP; p++) { aw[p] = __expf(aw[p] - mx); se += aw[p]; }
    const float inv = 1.f / se;

    const float* op = off + (size_t)bq * (HH * PP * 2) + h * (PP * 2);
    const float* vb = val + (size_t)b * NVAL * CC + h * DH + d;

    float acc = 0.f;
#pragma unroll
    for (int p = 0; p < PP; p++) {
        float x = (rx + op[p * 2 + 0] * (1.f / BEV)) * (float)BEV - 0.5f;
        float y = (ry + op[p * 2 + 1] * (1.f / BEV)) * (float)BEV - 0.5f;
        float xf = floorf(x), yf = floorf(y);
        float lx = x - xf, ly = y - yf;
        int x0 = (int)xf, y0 = (int)yf;
        float w = aw[p] * inv;

        float s = 0.f;
#pragma unroll
        for (int c = 0; c < 4; c++) {
            int xi = x0 + (c & 1);
            int yi = y0 + (c >> 1);
            float wx = (c & 1) ? lx : (1.f - lx);
            float wy = (c >> 1) ? ly : (1.f - ly);
            bool vld = (xi >= 0) && (xi < BEV) && (yi >= 0) && (yi < BEV);
            int xc = min(max(xi, 0), BEV - 1);
            int yc = min(max(yi, 0), BEV - 1);
            float gv = vb[(size_t)(yc * BEV + xc) * CC];
            s += vld ? (wx * wy * gv) : 0.f;
        }
        acc = fmaf(w, s, acc);
    }
    out[(size_t)bq * CC + t] = acc;
}

// ---------------------------------------------------------------------------
extern "C" void kernel_launch(void* const* d_in, const int* in_sizes, int n_in,
                              void* d_out, int out_size, void* d_ws, size_t ws_size,
                              hipStream_t stream) {
    const float* query   = (const float*)d_in[0];
    const float* value   = (const float*)d_in[1];
    const float* qpos    = (const float*)d_in[2];
    const float* ref2d   = (const float*)d_in[3];
    const float* in_w    = (const float*)d_in[4];
    const float* in_b    = (const float*)d_in[5];
    const float* outp_w  = (const float*)d_in[6];
    const float* outp_b  = (const float*)d_in[7];
    const float* off_w   = (const float*)d_in[8];
    const float* off_b   = (const float*)d_in[9];
    const float* aw_w    = (const float*)d_in[10];
    const float* aw_b    = (const float*)d_in[11];
    const float* vproj_w = (const float*)d_in[12];
    const float* vproj_b = (const float*)d_in[13];
    const float* oproj_w = (const float*)d_in[14];
    const float* oproj_b = (const float*)d_in[15];
    const float* ffn_w1  = (const float*)d_in[16];
    const float* ffn_b1  = (const float*)d_in[17];
    const float* ffn_w2  = (const float*)d_in[18];
    const float* ffn_b2  = (const float*)d_in[19];
    const float* ln1_g = (const float*)d_in[20], *ln1_b = (const float*)d_in[21];
    const float* ln2_g = (const float*)d_in[22], *ln2_b = (const float*)d_in[23];
    const float* ln3_g = (const float*)d_in[24], *ln3_b = (const float*)d_in[25];

    float* ws = (float*)d_ws;
    float* out = (float*)d_out;

    const int    M = BB * NQ;                 // 10000
    const size_t R = (size_t)M * CC;          // 2,560,000 floats

    // --- workspace layout (floats) ---
    float* QP   = ws;
    float* Qb   = ws + 1 * R;
    float* Kb   = ws + 2 * R;
    float* Vb   = ws + 3 * R;
    float* SA   = ws + 4 * R;
    float* ATT  = ws + 5 * R;
    float* VAL  = ws;                          // 40.96M floats, written later
    const size_t P0 = (size_t)BB * NVAL * CC;  // 40,960,000
    float* X1   = ws + P0;
    float* XLN1 = ws + P0 + 1 * R;
    float* OFF  = ws + P0 + 2 * R;
    float* AWL  = ws + P0 + 2 * R + 1280000;
    float* SAMP = ws + P0 + 2 * R + 1920000;
    float* CA   = ws + P0 + 3 * R + 1920000;
    float* XLN2 = ws + P0 + 4 * R + 1920000;
    float* FFNH = ws + P0 + 5 * R + 1920000;
    float* FFNO = ws + P0 + 7 * R + 1920000;

    dim3 blk(256);
    const int mg = (M + BM - 1) / BM;    // 157

    // 1. qp = query + query_pos
    add_vec<<<dim3((int)(R / 4 + 255) / 256), blk, 0, stream>>>(query, qpos, QP, (int)(R / 4));
    // 2-4. q, k, v projections
    gemm_bias<false><<<dim3(CC / BN, mg), blk, 0, stream>>>(QP,    in_w,               in_b,           Qb, M, CC, CC);
    gemm_bias<false><<<dim3(CC / BN, mg), blk, 0, stream>>>(query, in_w + CC * CC,     in_b + CC,      Kb, M, CC, CC);
    gemm_bias<false><<<dim3(CC / BN, mg), blk, 0, stream>>>(query, in_w + 2 * CC * CC, in_b + 2 * CC,  Vb, M, CC, CC);
    // 5. flash self-attention (tiled LDS GEMM)
    flash_tile<<<dim3(NT, BB * HH), blk, 0, stream>>>(Qb, Kb, Vb, ATT);
    // 6. out_proj
    gemm_bias<false><<<dim3(CC / BN, mg), blk, 0, stream>>>(ATT, outp_w, outp_b, SA, M, CC, CC);
    // 7. x1 = sa + query; xln1 = LN1(x1)
    resid_ln<<<dim3(M), blk, 0, stream>>>(SA, query, ln1_g, ln1_b, X1, XLN1);
    // 8. value projection (the big GEMM) — 128x128 tile, 2500 blocks
    gemm_bias128<<<dim3(CC / GN, (BB * NVAL) / GM), blk, 0, stream>>>(value, vproj_w, vproj_b, VAL, BB * NVAL, CC, CC);
    // 9-10. offsets + attention-weight logits
    gemm_bias<false><<<dim3(128 / BN, mg), blk, 0, stream>>>(XLN1, off_w, off_b, OFF, M, 128, CC);
    gemm_bias<false><<<dim3(64 / BN, mg),  blk, 0, stream>>>(XLN1, aw_w,  aw_b,  AWL, M, 64,  CC);
    // 11. bilinear sampling + weighted sum
    deform_sample<<<dim3(M), blk, 0, stream>>>(VAL, OFF, AWL, ref2d, SAMP);
    // 12. output projection of deform attn
    gemm_bias<false><<<dim3(CC / BN, mg), blk, 0, stream>>>(SAMP, oproj_w, oproj_b, CA, M, CC, CC);
    // 13. x2 = ca + x1; xln2 = LN2(x2)
    resid_ln<<<dim3(M), blk, 0, stream>>>(CA, X1, ln2_g, ln2_b, nullptr, XLN2);
    // 14-15. FFN
    gemm_bias<true ><<<dim3(DFFN / BN, mg), blk, 0, stream>>>(XLN2, ffn_w1, ffn_b1, FFNH, M, DFFN, CC);
    gemm_bias<false><<<dim3(CC / BN, mg),   blk, 0, stream>>>(FFNH, ffn_w2, ffn_b2, FFNO, M, CC, DFFN);
    // 16. out = LN3(xln2 + ffn_out)
    resid_ln<<<dim3(M), blk, 0, stream>>>(FFNO, XLN2, ln3_g, ln3_b, nullptr, out);
}

// Round 4
// 1072.949 us; speedup vs baseline: 2.2628x; 1.2928x over previous
//
#include <hip/hip_runtime.h>

#define BB   4
#define NQ   2500
#define CC   256
#define HH   8
#define PP   8
#define DFFN 512
#define DH   32
#define BEV  200
#define NVAL (BEV * BEV)

typedef short bf16x8 __attribute__((ext_vector_type(8)));
typedef float f32x4  __attribute__((ext_vector_type(4)));

__device__ __forceinline__ unsigned short f2b(float f) {
    union { float f; unsigned int u; } v; v.f = f;
    unsigned int r = v.u + 0x7fffu + ((v.u >> 16) & 1u);   // RNE
    return (unsigned short)(r >> 16);
}
__device__ __forceinline__ float b2f(unsigned short b) {
    union { unsigned int u; float f; } v; v.u = ((unsigned int)b) << 16;
    return v.f;
}

#define GLOAD16(g, l)                                                         \
    __builtin_amdgcn_global_load_lds(                                         \
        (const __attribute__((address_space(1))) void*)(g),                   \
        (__attribute__((address_space(3))) void*)(l), 16, 0, 0)

// ---------------------------------------------------------------------------
// fused (query+qpos)->bf16 and query->bf16
// ---------------------------------------------------------------------------
__global__ __launch_bounds__(256) void add_cvt_qp(const float* __restrict__ q,
                                                  const float* __restrict__ p,
                                                  unsigned short* __restrict__ qpb,
                                                  unsigned short* __restrict__ qb,
                                                  int n4) {
    int i = blockIdx.x * 256 + threadIdx.x;
    if (i < n4) {
        float4 a = reinterpret_cast<const float4*>(q)[i];
        float4 b = reinterpret_cast<const float4*>(p)[i];
        ushort4 s, t;
        s.x = f2b(a.x); s.y = f2b(a.y); s.z = f2b(a.z); s.w = f2b(a.w);
        t.x = f2b(a.x + b.x); t.y = f2b(a.y + b.y);
        t.z = f2b(a.z + b.z); t.w = f2b(a.w + b.w);
        reinterpret_cast<ushort4*>(qb)[i]  = s;
        reinterpret_cast<ushort4*>(qpb)[i] = t;
    }
}

// generic fp32 -> bf16
__global__ __launch_bounds__(256) void cvt4(const float* __restrict__ in,
                                            unsigned short* __restrict__ out, int n4) {
    int i = blockIdx.x * 256 + threadIdx.x;
    if (i < n4) {
        float4 a = reinterpret_cast<const float4*>(in)[i];
        ushort4 s;
        s.x = f2b(a.x); s.y = f2b(a.y); s.z = f2b(a.z); s.w = f2b(a.w);
        reinterpret_cast<ushort4*>(out)[i] = s;
    }
}

// all weight matrices -> one bf16 arena (f4-index ranges hardcoded)
__global__ __launch_bounds__(256) void cvt_weights(const float* __restrict__ in_w,
                                                   const float* __restrict__ outp_w,
                                                   const float* __restrict__ vproj_w,
                                                   const float* __restrict__ oproj_w,
                                                   const float* __restrict__ ffn_w1,
                                                   const float* __restrict__ ffn_w2,
                                                   unsigned short* __restrict__ Wb) {
    int i = blockIdx.x * 256 + threadIdx.x;      // float4 index, < 163840
    if (i >= 163840) return;
    const float* src; int base;
    if      (i <  49152) { src = in_w;    base = 0;      }
    else if (i <  65536) { src = outp_w;  base = 49152;  }
    else if (i <  81920) { src = vproj_w; base = 65536;  }
    else if (i <  98304) { src = oproj_w; base = 81920;  }
    else if (i < 131072) { src = ffn_w1;  base = 98304;  }
    else                 { src = ffn_w2;  base = 131072; }
    float4 a = reinterpret_cast<const float4*>(src)[i - base];
    ushort4 s;
    s.x = f2b(a.x); s.y = f2b(a.y); s.z = f2b(a.z); s.w = f2b(a.w);
    reinterpret_cast<ushort4*>(Wb)[i] = s;
}

// ---------------------------------------------------------------------------
// bf16 MFMA GEMM: C[M,N] = A[M,K](bf16) @ W[N,K](bf16)^T + bias(f32)
// 128x128 tile, BK=32, 4 waves (2x2), each wave 64x64 = 4x4 frags 16x16x32.
// global_load_lds 16B staging, linear LDS. N multiple of 128.
// ---------------------------------------------------------------------------
#define TM 128
#define TN 128
#define TK 32
template <bool RELU, bool OBF>
__global__ __launch_bounds__(256) void gemm_mfma(const unsigned short* __restrict__ A,
                                                 const unsigned short* __restrict__ W,
                                                 const float* __restrict__ bias,
                                                 float* __restrict__ Cf,
                                                 unsigned short* __restrict__ Cb,
                                                 int M, int N, int K) {
    __shared__ __align__(16) unsigned short As[TM * TK];
    __shared__ __align__(16) unsigned short Ws[TN * TK];
    const int t    = threadIdx.x;
    const int lane = t & 63;
    const int wv   = t >> 6;
    const int wr   = wv >> 1;
    const int wc   = wv & 1;
    const int m0 = blockIdx.y * TM;
    const int n0 = blockIdx.x * TN;
    const int l15 = lane & 15;
    const int l4  = lane >> 4;

    // staging map: chunk c (0..7): lane -> row = c*16 + (lane>>2), k = (lane&3)*8
    const int srow = (lane >> 2);
    const int skk  = (lane & 3) << 3;

    f32x4 acc[4][4];
#pragma unroll
    for (int i = 0; i < 4; i++)
#pragma unroll
        for (int j = 0; j < 4; j++) acc[i][j] = (f32x4){0.f, 0.f, 0.f, 0.f};

    for (int k0 = 0; k0 < K; k0 += TK) {
#pragma unroll
        for (int c2 = 0; c2 < 2; c2++) {
            const int c = wv * 2 + c2;
            const int row = c * 16 + srow;
            int ar = m0 + row; if (ar >= M) ar = M - 1;
            int br = n0 + row; if (br >= N) br = N - 1;
            GLOAD16(A + (size_t)ar * K + k0 + skk, As + c * 512);
            GLOAD16(W + (size_t)br * K + k0 + skk, Ws + c * 512);
        }
        __syncthreads();

        bf16x8 af[4], bfr[4];
#pragma unroll
        for (int i = 0; i < 4; i++) {
            af[i]  = *reinterpret_cast<const bf16x8*>(&As[(wr * 64 + i * 16 + l15) * TK + l4 * 8]);
            bfr[i] = *reinterpret_cast<const bf16x8*>(&Ws[(wc * 64 + i * 16 + l15) * TK + l4 * 8]);
        }
#pragma unroll
        for (int i = 0; i < 4; i++)
#pragma unroll
            for (int j = 0; j < 4; j++)
                acc[i][j] = __builtin_amdgcn_mfma_f32_16x16x32_bf16(af[i], bfr[j], acc[i][j], 0, 0, 0);
        __syncthreads();
    }

#pragma unroll
    for (int i = 0; i < 4; i++) {
#pragma unroll
        for (int j = 0; j < 4; j++) {
            const int col = n0 + wc * 64 + j * 16 + l15;
            const float bv = bias[col];
#pragma unroll
            for (int r = 0; r < 4; r++) {
                const int row = m0 + wr * 64 + i * 16 + l4 * 4 + r;
                if (row < M) {
                    float v = acc[i][j][r] + bv;
                    if (RELU) v = fmaxf(v, 0.f);
                    if (OBF) Cb[(size_t)row * N + col] = f2b(v);
                    else     Cf[(size_t)row * N + col] = v;
                }
            }
        }
    }
}

// ---------------------------------------------------------------------------
// fp32 tiled GEMM (64x64) — only for small-N off/aw projections
// ---------------------------------------------------------------------------
#define BM 64
#define BN 64
#define BK 16
__global__ __launch_bounds__(256) void gemm_bias(const float* __restrict__ A,
                                                 const float* __restrict__ W,
                                                 const float* __restrict__ bias,
                                                 float* __restrict__ C,
                                                 int M, int N, int K) {
    __shared__ float As[BK][BM + 4];
    __shared__ float Ws[BK][BN + 4];
    const int m0 = blockIdx.y * BM;
    const int n0 = blockIdx.x * BN;
    const int t  = threadIdx.x;
    const int tx = t & 15;
    const int ty = t >> 4;
    const int lrow = t >> 2;
    const int lk   = (t & 3) << 2;

    float acc[4][4];
#pragma unroll
    for (int i = 0; i < 4; i++)
#pragma unroll
        for (int j = 0; j < 4; j++) acc[i][j] = 0.f;

    const bool aok = (m0 + lrow) < M;
    const float* Ap = A + (size_t)(m0 + lrow) * K + lk;
    const float* Wp = W + (size_t)(n0 + lrow) * K + lk;

    for (int k0 = 0; k0 < K; k0 += BK) {
        float4 av = make_float4(0.f, 0.f, 0.f, 0.f);
        if (aok) av = *reinterpret_cast<const float4*>(Ap + k0);
        float4 wv = *reinterpret_cast<const float4*>(Wp + k0);
        As[lk + 0][lrow] = av.x; As[lk + 1][lrow] = av.y;
        As[lk + 2][lrow] = av.z; As[lk + 3][lrow] = av.w;
        Ws[lk + 0][lrow] = wv.x; Ws[lk + 1][lrow] = wv.y;
        Ws[lk + 2][lrow] = wv.z; Ws[lk + 3][lrow] = wv.w;
        __syncthreads();
#pragma unroll
        for (int kk = 0; kk < BK; kk++) {
            float4 a4 = *reinterpret_cast<const float4*>(&As[kk][ty << 2]);
            float4 w4 = *reinterpret_cast<const float4*>(&Ws[kk][tx << 2]);
            float a[4] = {a4.x, a4.y, a4.z, a4.w};
            float w[4] = {w4.x, w4.y, w4.z, w4.w};
#pragma unroll
            for (int i = 0; i < 4; i++)
#pragma unroll
                for (int j = 0; j < 4; j++)
                    acc[i][j] = fmaf(a[i], w[j], acc[i][j]);
        }
        __syncthreads();
    }

    float4 b4 = *reinterpret_cast<const float4*>(bias + n0 + (tx << 2));
#pragma unroll
    for (int i = 0; i < 4; i++) {
        int row = m0 + (ty << 2) + i;
        if (row < M) {
            float4 o;
            o.x = acc[i][0] + b4.x; o.y = acc[i][1] + b4.y;
            o.z = acc[i][2] + b4.z; o.w = acc[i][3] + b4.w;
            *reinterpret_cast<float4*>(C + (size_t)row * N + n0 + (tx << 2)) = o;
        }
    }
}

// ---------------------------------------------------------------------------
// flash self-attention (fp32 tile GEMM, unchanged) — now stores bf16
// ---------------------------------------------------------------------------
#define QT 64
#define NT ((NQ + QT - 1) / QT)   // 40
__global__ __launch_bounds__(256, 2) void flash_tile(const float* __restrict__ Q,
                                                     const float* __restrict__ Kb,
                                                     const float* __restrict__ Vb,
                                                     unsigned short* __restrict__ O) {
    __shared__ float Qs[DH][QT + 4];
    __shared__ float Ks[DH][QT + 4];
    __shared__ float Vs[QT][DH + 4];
    __shared__ float Ps[QT][QT + 4];

    const int bh = blockIdx.y;
    const int b = bh >> 3, h = bh & 7;
    const int t = threadIdx.x;
    const int tx = t & 15;
    const int ty = t >> 4;
    const int lrow = t >> 2;
    const int lk8  = (t & 3) << 3;
    const int q0 = blockIdx.x * QT;
    const float scale = 0.17677669529663687f;

    {
        int qr = q0 + lrow; if (qr >= NQ) qr = NQ - 1;
        const float* qp = Q + ((size_t)b * NQ + qr) * CC + h * DH + lk8;
        float4 qa = *reinterpret_cast<const float4*>(qp);
        float4 qb2 = *reinterpret_cast<const float4*>(qp + 4);
        Qs[lk8 + 0][lrow] = qa.x * scale;  Qs[lk8 + 1][lrow] = qa.y * scale;
        Qs[lk8 + 2][lrow] = qa.z * scale;  Qs[lk8 + 3][lrow] = qa.w * scale;
        Qs[lk8 + 4][lrow] = qb2.x * scale; Qs[lk8 + 5][lrow] = qb2.y * scale;
        Qs[lk8 + 6][lrow] = qb2.z * scale; Qs[lk8 + 7][lrow] = qb2.w * scale;
    }

    const size_t kvbase = (size_t)b * NQ * CC + (size_t)h * DH + lk8;

    float4 pk0, pk1, pv0, pv1;
    {
        const float* kp = Kb + kvbase + (size_t)lrow * CC;
        const float* vp = Vb + kvbase + (size_t)lrow * CC;
        pk0 = *reinterpret_cast<const float4*>(kp);
        pk1 = *reinterpret_cast<const float4*>(kp + 4);
        pv0 = *reinterpret_cast<const float4*>(vp);
        pv1 = *reinterpret_cast<const float4*>(vp + 4);
    }

    float m[4], l[4], o[4][2];
#pragma unroll
    for (int i = 0; i < 4; i++) {
        m[i] = -1e30f; l[i] = 0.f; o[i][0] = 0.f; o[i][1] = 0.f;
    }

    for (int kt = 0; kt < NT; kt++) {
        __syncthreads();
        Ks[lk8 + 0][lrow] = pk0.x; Ks[lk8 + 1][lrow] = pk0.y;
        Ks[lk8 + 2][lrow] = pk0.z; Ks[lk8 + 3][lrow] = pk0.w;
        Ks[lk8 + 4][lrow] = pk1.x; Ks[lk8 + 5][lrow] = pk1.y;
        Ks[lk8 + 6][lrow] = pk1.z; Ks[lk8 + 7][lrow] = pk1.w;
        *reinterpret_cast<float4*>(&Vs[lrow][lk8])     = pv0;
        *reinterpret_cast<float4*>(&Vs[lrow][lk8 + 4]) = pv1;
        __syncthreads();

        if (kt + 1 < NT) {
            int kr = (kt + 1) * QT + lrow; if (kr >= NQ) kr = NQ - 1;
            const float* kp = Kb + kvbase + (size_t)kr * CC;
            const float* vp = Vb + kvbase + (size_t)kr * CC;
            pk0 = *reinterpret_cast<const float4*>(kp);
            pk1 = *reinterpret_cast<const float4*>(kp + 4);
            pv0 = *reinterpret_cast<const float4*>(vp);
            pv1 = *reinterpret_cast<const float4*>(vp + 4);
        }

        float s[4][4];
#pragma unroll
        for (int i = 0; i < 4; i++)
#pragma unroll
            for (int j = 0; j < 4; j++) s[i][j] = 0.f;
#pragma unroll
        for (int kk = 0; kk < DH; kk++) {
            float4 a4 = *reinterpret_cast<const float4*>(&Qs[kk][ty << 2]);
            float4 k4 = *reinterpret_cast<const float4*>(&Ks[kk][tx << 2]);
            float a[4] = {a4.x, a4.y, a4.z, a4.w};
            float kv[4] = {k4.x, k4.y, k4.z, k4.w};
#pragma unroll
            for (int i = 0; i < 4; i++)
#pragma unroll
                for (int j = 0; j < 4; j++)
                    s[i][j] = fmaf(a[i], kv[j], s[i][j]);
        }

        if (kt == NT - 1) {
            const int rem = NQ - kt * QT;
#pragma unroll
            for (int j = 0; j < 4; j++)
                if (tx * 4 + j >= rem) {
#pragma unroll
                    for (int i = 0; i < 4; i++) s[i][j] = -1e30f;
                }
        }

#pragma unroll
        for (int i = 0; i < 4; i++) {
            float rm = fmaxf(fmaxf(s[i][0], s[i][1]), fmaxf(s[i][2], s[i][3]));
            rm = fmaxf(rm, __shfl_xor(rm, 1));
            rm = fmaxf(rm, __shfl_xor(rm, 2));
            rm = fmaxf(rm, __shfl_xor(rm, 4));
            rm = fmaxf(rm, __shfl_xor(rm, 8));
            float mn = fmaxf(m[i], rm);
            float cor = __expf(m[i] - mn);
            m[i] = mn;
            float p0 = __expf(s[i][0] - mn);
            float p1 = __expf(s[i][1] - mn);
            float p2 = __expf(s[i][2] - mn);
            float p3 = __expf(s[i][3] - mn);
            float rs = p0 + p1 + p2 + p3;
            rs += __shfl_xor(rs, 1);
            rs += __shfl_xor(rs, 2);
            rs += __shfl_xor(rs, 4);
            rs += __shfl_xor(rs, 8);
            l[i] = l[i] * cor + rs;
            o[i][0] *= cor; o[i][1] *= cor;
            *reinterpret_cast<float4*>(&Ps[(ty << 2) + i][tx << 2]) = make_float4(p0, p1, p2, p3);
        }
        __syncthreads();

#pragma unroll
        for (int kk0 = 0; kk0 < QT; kk0 += 4) {
            float4 p4[4];
#pragma unroll
            for (int i = 0; i < 4; i++)
                p4[i] = *reinterpret_cast<const float4*>(&Ps[(ty << 2) + i][kk0]);
            float2 v4[4];
#pragma unroll
            for (int r = 0; r < 4; r++)
                v4[r] = *reinterpret_cast<const float2*>(&Vs[kk0 + r][tx << 1]);
#pragma unroll
            for (int i = 0; i < 4; i++) {
                float pr[4] = {p4[i].x, p4[i].y, p4[i].z, p4[i].w};
#pragma unroll
                for (int r = 0; r < 4; r++) {
                    o[i][0] = fmaf(pr[r], v4[r].x, o[i][0]);
                    o[i][1] = fmaf(pr[r], v4[r].y, o[i][1]);
                }
            }
        }
    }

#pragma unroll
    for (int i = 0; i < 4; i++) {
        int row = q0 + (ty << 2) + i;
        if (row < NQ) {
            float inv = 1.f / l[i];
            unsigned int pack = (unsigned int)f2b(o[i][0] * inv)
                              | ((unsigned int)f2b(o[i][1] * inv) << 16);
            *reinterpret_cast<unsigned int*>(
                O + ((size_t)b * NQ + row) * CC + h * DH + (tx << 1)) = pack;
        }
    }
}

// ---------------------------------------------------------------------------
// fused residual + LayerNorm (optional bf16 copy of ln_out)
// ---------------------------------------------------------------------------
__global__ __launch_bounds__(256) void resid_ln(const float* __restrict__ a,
                                                const float* __restrict__ r,
                                                const float* __restrict__ g,
                                                const float* __restrict__ be,
                                                float* __restrict__ sum_out,
                                                float* __restrict__ ln_out,
                                                unsigned short* __restrict__ ln_bf) {
    const int row = blockIdx.x;
    const int t = threadIdx.x;
    const size_t base = (size_t)row * CC;
    float v = a[base + t] + r[base + t];
    if (sum_out) sum_out[base + t] = v;

    __shared__ float red[4];
    float s = v;
#pragma unroll
    for (int o = 1; o < 64; o <<= 1) s += __shfl_xor(s, o, 64);
    if ((t & 63) == 0) red[t >> 6] = s;
    __syncthreads();
    float mean = (red[0] + red[1] + red[2] + red[3]) * (1.f / 256.f);
    __syncthreads();

    float d = v - mean;
    float sq = d * d;
#pragma unroll
    for (int o = 1; o < 64; o <<= 1) sq += __shfl_xor(sq, o, 64);
    if ((t & 63) == 0) red[t >> 6] = sq;
    __syncthreads();
    float var = (red[0] + red[1] + red[2] + red[3]) * (1.f / 256.f);

    float res = d * rsqrtf(var + 1e-5f) * g[t] + be[t];
    ln_out[base + t] = res;
    if (ln_bf) ln_bf[base + t] = f2b(res);
}

// ---------------------------------------------------------------------------
// deformable sampling: val is bf16, output bf16
// ---------------------------------------------------------------------------
__global__ __launch_bounds__(256) void deform_sample(const unsigned short* __restrict__ val,
                                                     const float* __restrict__ off,
                                                     const float* __restrict__ awl,
                                                     const float* __restrict__ ref,
                                                     unsigned short* __restrict__ out) {
    const int bq = blockIdx.x;
    const int b = bq / NQ;
    const int t = threadIdx.x;
    const int h = t >> 5, d = t & 31;

    const float rx = ref[(size_t)bq * 2 + 0];
    const float ry = ref[(size_t)bq * 2 + 1];

    const float* ap = awl + (size_t)bq * (HH * PP) + h * PP;
    float aw[PP];
    float mx = -1e30f;
#pragma unroll
    for (int p = 0; p < PP; p++) { aw[p] = ap[p]; mx = fmaxf(mx, aw[p]); }
    float se = 0.f;
#pragma unroll
    for (int p = 0; p < PP; p++) { aw[p] = __expf(aw[p] - mx); se += aw[p]; }
    const float inv = 1.f / se;

    const float* op = off + (size_t)bq * (HH * PP * 2) + h * (PP * 2);
    const unsigned short* vb = val + (size_t)b * NVAL * CC + h * DH + d;

    float acc = 0.f;
#pragma unroll
    for (int p = 0; p < PP; p++) {
        float x = (rx + op[p * 2 + 0] * (1.f / BEV)) * (float)BEV - 0.5f;
        float y = (ry + op[p * 2 + 1] * (1.f / BEV)) * (float)BEV - 0.5f;
        float xf = floorf(x), yf = floorf(y);
        float lx = x - xf, ly = y - yf;
        int x0 = (int)xf, y0 = (int)yf;
        float w = aw[p] * inv;

        float s = 0.f;
#pragma unroll
        for (int c = 0; c < 4; c++) {
            int xi = x0 + (c & 1);
            int yi = y0 + (c >> 1);
            float wx = (c & 1) ? lx : (1.f - lx);
            float wy = (c >> 1) ? ly : (1.f - ly);
            bool vld = (xi >= 0) && (xi < BEV) && (yi >= 0) && (yi < BEV);
            int xc = min(max(xi, 0), BEV - 1);
            int yc = min(max(yi, 0), BEV - 1);
            float gv = b2f(vb[(size_t)(yc * BEV + xc) * CC]);
            s += vld ? (wx * wy * gv) : 0.f;
        }
        acc = fmaf(w, s, acc);
    }
    out[(size_t)bq * CC + t] = f2b(acc);
}

// ---------------------------------------------------------------------------
extern "C" void kernel_launch(void* const* d_in, const int* in_sizes, int n_in,
                              void* d_out, int out_size, void* d_ws, size_t ws_size,
                              hipStream_t stream) {
    const float* query   = (const float*)d_in[0];
    const float* value   = (const float*)d_in[1];
    const float* qpos    = (const float*)d_in[2];
    const float* ref2d   = (const float*)d_in[3];
    const float* in_w    = (const float*)d_in[4];
    const float* in_b    = (const float*)d_in[5];
    const float* outp_w  = (const float*)d_in[6];
    const float* outp_b  = (const float*)d_in[7];
    const float* off_w   = (const float*)d_in[8];
    const float* off_b   = (const float*)d_in[9];
    const float* aw_w    = (const float*)d_in[10];
    const float* aw_b    = (const float*)d_in[11];
    const float* vproj_w = (const float*)d_in[12];
    const float* vproj_b = (const float*)d_in[13];
    const float* oproj_w = (const float*)d_in[14];
    const float* oproj_b = (const float*)d_in[15];
    const float* ffn_w1  = (const float*)d_in[16];
    const float* ffn_b1  = (const float*)d_in[17];
    const float* ffn_w2  = (const float*)d_in[18];
    const float* ffn_b2  = (const float*)d_in[19];
    const float* ln1_g = (const float*)d_in[20], *ln1_b = (const float*)d_in[21];
    const float* ln2_g = (const float*)d_in[22], *ln2_b = (const float*)d_in[23];
    const float* ln3_g = (const float*)d_in[24], *ln3_b = (const float*)d_in[25];

    float* ws = (float*)d_ws;
    float* out = (float*)d_out;

    const int    M = BB * NQ;                 // 10000
    const size_t R = (size_t)M * CC;          // 2,560,000 floats

    // ---- workspace layout (float units; bf16 buffers take half) ----
    // Region1 [0, 20.48M fl): phase-A scratch, then VALUEb
    unsigned short* QPb    = (unsigned short*)ws;                    // 2.56M ush
    unsigned short* QUERYb = (unsigned short*)(ws + 1280000);
    float* Qb   = ws + 2560000;
    float* Kb   = ws + 5120000;
    float* Vb   = ws + 7680000;
    unsigned short* ATTb = (unsigned short*)(ws + 10240000);
    float* SA   = ws + 11520000;                                     // ..14.08M
    unsigned short* VALUEb = (unsigned short*)ws;                    // 40.96M ush
    // Region2 [20.48M, 40.96M fl): VALb (bf16)
    unsigned short* VALb = (unsigned short*)(ws + 20480000);         // 40.96M ush
    // Region3 [40.96M, ...):
    float* B3   = ws + 40960000;
    float* X1   = B3;
    float* XLN1 = B3 + 2560000;
    float* OFF  = B3 + 5120000;
    float* AWL  = B3 + 6400000;
    unsigned short* SAMPb = (unsigned short*)(B3 + 7040000);
    float* CA   = B3 + 8320000;
    float* XLN2 = B3 + 10880000;
    unsigned short* XLN2b = (unsigned short*)(B3 + 13440000);
    unsigned short* FFNHb = (unsigned short*)(B3 + 14720000);
    float* FFNO = B3 + 17280000;
    unsigned short* Wb = (unsigned short*)(B3 + 19840000);
    // end: 40.96M + 20.17M = 61.13M floats = 244.5 MB

    dim3 blk(256);
    const int mgT = (M + TM - 1) / TM;    // 79

    // 1. bf16 conversions
    add_cvt_qp<<<dim3(2500), blk, 0, stream>>>(query, qpos, QPb, QUERYb, 640000);
    cvt_weights<<<dim3(640), blk, 0, stream>>>(in_w, outp_w, vproj_w, oproj_w, ffn_w1, ffn_w2, Wb);
    // 2-4. q, k, v projections (bf16 MFMA, f32 out)
    gemm_mfma<false, false><<<dim3(2, mgT), blk, 0, stream>>>(QPb,    Wb,          in_b,       Qb, nullptr, M, CC, CC);
    gemm_mfma<false, false><<<dim3(2, mgT), blk, 0, stream>>>(QUERYb, Wb + 65536,  in_b + CC,  Kb, nullptr, M, CC, CC);
    gemm_mfma<false, false><<<dim3(2, mgT), blk, 0, stream>>>(QUERYb, Wb + 131072, in_b + 2*CC, Vb, nullptr, M, CC, CC);
    // 5. flash self-attention -> bf16
    flash_tile<<<dim3(NT, BB * HH), blk, 0, stream>>>(Qb, Kb, Vb, ATTb);
    // 6. out_proj
    gemm_mfma<false, false><<<dim3(2, mgT), blk, 0, stream>>>(ATTb, Wb + 196608, outp_b, SA, nullptr, M, CC, CC);
    // 7. x1 = sa + query; xln1 = LN1(x1)
    resid_ln<<<dim3(M), blk, 0, stream>>>(SA, query, ln1_g, ln1_b, X1, XLN1, nullptr);
    // 8-9. offsets + aw logits (fp32 small GEMMs)
    gemm_bias<<<dim3(2, (M + BM - 1) / BM), blk, 0, stream>>>(XLN1, off_w, off_b, OFF, M, 128, CC);
    gemm_bias<<<dim3(1, (M + BM - 1) / BM), blk, 0, stream>>>(XLN1, aw_w,  aw_b,  AWL, M, 64,  CC);
    // 10. value -> bf16  (region1 now dead)
    cvt4<<<dim3(40000), blk, 0, stream>>>(value, VALUEb, 10240000);
    // 11. value projection (bf16 MFMA, bf16 out)
    gemm_mfma<false, true><<<dim3(2, (BB * NVAL) / TM), blk, 0, stream>>>(VALUEb, Wb + 262144, vproj_b, nullptr, VALb, BB * NVAL, CC, CC);
    // 12. bilinear sampling -> bf16
    deform_sample<<<dim3(M), blk, 0, stream>>>(VALb, OFF, AWL, ref2d, SAMPb);
    // 13. output projection of deform attn
    gemm_mfma<false, false><<<dim3(2, mgT), blk, 0, stream>>>(SAMPb, Wb + 327680, oproj_b, CA, nullptr, M, CC, CC);
    // 14. x2 = ca + x1; xln2 = LN2(x2) (+bf16 copy)
    resid_ln<<<dim3(M), blk, 0, stream>>>(CA, X1, ln2_g, ln2_b, nullptr, XLN2, XLN2b);
    // 15-16. FFN (bf16 MFMA; hidden kept bf16 with fused ReLU)
    gemm_mfma<true,  true ><<<dim3(4, mgT), blk, 0, stream>>>(XLN2b, Wb + 393216, ffn_b1, nullptr, FFNHb, M, DFFN, CC);
    gemm_mfma<false, false><<<dim3(2, mgT), blk, 0, stream>>>(FFNHb, Wb + 524288, ffn_b2, FFNO, nullptr, M, CC, DFFN);
    // 17. out = LN3(ffn_out + xln2)
    resid_ln<<<dim3(M), blk, 0, stream>>>(FFNO, XLN2, ln3_g, ln3_b, nullptr, out, nullptr);
}

// Round 5
// 680.891 us; speedup vs baseline: 3.5658x; 1.5758x over previous
//
#include <hip/hip_runtime.h>

#define BB   4
#define NQ   2500
#define CC   256
#define HH   8
#define PP   8
#define DFFN 512
#define DH   32
#define BEV  200
#define NVAL (BEV * BEV)

typedef short bf16x8 __attribute__((ext_vector_type(8)));
typedef float f32x4  __attribute__((ext_vector_type(4)));

__device__ __forceinline__ unsigned short f2b(float f) {
    union { float f; unsigned int u; } v; v.f = f;
    unsigned int r = v.u + 0x7fffu + ((v.u >> 16) & 1u);   // RNE
    return (unsigned short)(r >> 16);
}
__device__ __forceinline__ float b2f(unsigned short b) {
    union { unsigned int u; float f; } v; v.u = ((unsigned int)b) << 16;
    return v.f;
}

#define GLOAD16(g, l)                                                         \
    __builtin_amdgcn_global_load_lds(                                         \
        (const __attribute__((address_space(1))) void*)(g),                   \
        (__attribute__((address_space(3))) void*)(l), 16, 0, 0)

// ---------------------------------------------------------------------------
// fused (query+qpos)->bf16 and query->bf16
// ---------------------------------------------------------------------------
__global__ __launch_bounds__(256) void add_cvt_qp(const float* __restrict__ q,
                                                  const float* __restrict__ p,
                                                  unsigned short* __restrict__ qpb,
                                                  unsigned short* __restrict__ qb,
                                                  int n4) {
    int i = blockIdx.x * 256 + threadIdx.x;
    if (i < n4) {
        float4 a = reinterpret_cast<const float4*>(q)[i];
        float4 b = reinterpret_cast<const float4*>(p)[i];
        ushort4 s, t;
        s.x = f2b(a.x); s.y = f2b(a.y); s.z = f2b(a.z); s.w = f2b(a.w);
        t.x = f2b(a.x + b.x); t.y = f2b(a.y + b.y);
        t.z = f2b(a.z + b.z); t.w = f2b(a.w + b.w);
        reinterpret_cast<ushort4*>(qb)[i]  = s;
        reinterpret_cast<ushort4*>(qpb)[i] = t;
    }
}

// generic fp32 -> bf16
__global__ __launch_bounds__(256) void cvt4(const float* __restrict__ in,
                                            unsigned short* __restrict__ out, int n4) {
    int i = blockIdx.x * 256 + threadIdx.x;
    if (i < n4) {
        float4 a = reinterpret_cast<const float4*>(in)[i];
        ushort4 s;
        s.x = f2b(a.x); s.y = f2b(a.y); s.z = f2b(a.z); s.w = f2b(a.w);
        reinterpret_cast<ushort4*>(out)[i] = s;
    }
}

// all weight matrices -> one bf16 arena (f4-index ranges hardcoded)
__global__ __launch_bounds__(256) void cvt_weights(const float* __restrict__ in_w,
                                                   const float* __restrict__ outp_w,
                                                   const float* __restrict__ vproj_w,
                                                   const float* __restrict__ oproj_w,
                                                   const float* __restrict__ ffn_w1,
                                                   const float* __restrict__ ffn_w2,
                                                   unsigned short* __restrict__ Wb) {
    int i = blockIdx.x * 256 + threadIdx.x;      // float4 index, < 163840
    if (i >= 163840) return;
    const float* src; int base;
    if      (i <  49152) { src = in_w;    base = 0;      }
    else if (i <  65536) { src = outp_w;  base = 49152;  }
    else if (i <  81920) { src = vproj_w; base = 65536;  }
    else if (i <  98304) { src = oproj_w; base = 81920;  }
    else if (i < 131072) { src = ffn_w1;  base = 98304;  }
    else                 { src = ffn_w2;  base = 131072; }
    float4 a = reinterpret_cast<const float4*>(src)[i - base];
    ushort4 s;
    s.x = f2b(a.x); s.y = f2b(a.y); s.z = f2b(a.z); s.w = f2b(a.w);
    reinterpret_cast<ushort4*>(Wb)[i] = s;
}

// ---------------------------------------------------------------------------
// bf16 MFMA GEMM: C[M,N] = A[M,K](bf16) @ W[N,K](bf16)^T + bias(f32)
// 128x128 tile, BK=32, 4 waves (2x2), each wave 64x64 = 4x4 frags 16x16x32.
// ---------------------------------------------------------------------------
#define TM 128
#define TN 128
#define TK 32
template <bool RELU, bool OBF>
__global__ __launch_bounds__(256) void gemm_mfma(const unsigned short* __restrict__ A,
                                                 const unsigned short* __restrict__ W,
                                                 const float* __restrict__ bias,
                                                 float* __restrict__ Cf,
                                                 unsigned short* __restrict__ Cb,
                                                 int M, int N, int K) {
    __shared__ __align__(16) unsigned short As[TM * TK];
    __shared__ __align__(16) unsigned short Ws[TN * TK];
    const int t    = threadIdx.x;
    const int lane = t & 63;
    const int wv   = t >> 6;
    const int wr   = wv >> 1;
    const int wc   = wv & 1;
    const int m0 = blockIdx.y * TM;
    const int n0 = blockIdx.x * TN;
    const int l15 = lane & 15;
    const int l4  = lane >> 4;

    const int srow = (lane >> 2);
    const int skk  = (lane & 3) << 3;

    f32x4 acc[4][4];
#pragma unroll
    for (int i = 0; i < 4; i++)
#pragma unroll
        for (int j = 0; j < 4; j++) acc[i][j] = (f32x4){0.f, 0.f, 0.f, 0.f};

    for (int k0 = 0; k0 < K; k0 += TK) {
#pragma unroll
        for (int c2 = 0; c2 < 2; c2++) {
            const int c = wv * 2 + c2;
            const int row = c * 16 + srow;
            int ar = m0 + row; if (ar >= M) ar = M - 1;
            int br = n0 + row; if (br >= N) br = N - 1;
            GLOAD16(A + (size_t)ar * K + k0 + skk, As + c * 512);
            GLOAD16(W + (size_t)br * K + k0 + skk, Ws + c * 512);
        }
        __syncthreads();

        bf16x8 af[4], bfr[4];
#pragma unroll
        for (int i = 0; i < 4; i++) {
            af[i]  = *reinterpret_cast<const bf16x8*>(&As[(wr * 64 + i * 16 + l15) * TK + l4 * 8]);
            bfr[i] = *reinterpret_cast<const bf16x8*>(&Ws[(wc * 64 + i * 16 + l15) * TK + l4 * 8]);
        }
#pragma unroll
        for (int i = 0; i < 4; i++)
#pragma unroll
            for (int j = 0; j < 4; j++)
                acc[i][j] = __builtin_amdgcn_mfma_f32_16x16x32_bf16(af[i], bfr[j], acc[i][j], 0, 0, 0);
        __syncthreads();
    }

#pragma unroll
    for (int i = 0; i < 4; i++) {
#pragma unroll
        for (int j = 0; j < 4; j++) {
            const int col = n0 + wc * 64 + j * 16 + l15;
            const float bv = bias[col];
#pragma unroll
            for (int r = 0; r < 4; r++) {
                const int row = m0 + wr * 64 + i * 16 + l4 * 4 + r;
                if (row < M) {
                    float v = acc[i][j][r] + bv;
                    if (RELU) v = fmaxf(v, 0.f);
                    if (OBF) Cb[(size_t)row * N + col] = f2b(v);
                    else     Cf[(size_t)row * N + col] = v;
                }
            }
        }
    }
}

// ---------------------------------------------------------------------------
// fp32 tiled GEMM (64x64) — off/aw projections
// ---------------------------------------------------------------------------
#define BM 64
#define BN 64
#define BK 16
__global__ __launch_bounds__(256) void gemm_bias(const float* __restrict__ A,
                                                 const float* __restrict__ W,
                                                 const float* __restrict__ bias,
                                                 float* __restrict__ C,
                                                 int M, int N, int K) {
    __shared__ float As[BK][BM + 4];
    __shared__ float Ws[BK][BN + 4];
    const int m0 = blockIdx.y * BM;
    const int n0 = blockIdx.x * BN;
    const int t  = threadIdx.x;
    const int tx = t & 15;
    const int ty = t >> 4;
    const int lrow = t >> 2;
    const int lk   = (t & 3) << 2;

    float acc[4][4];
#pragma unroll
    for (int i = 0; i < 4; i++)
#pragma unroll
        for (int j = 0; j < 4; j++) acc[i][j] = 0.f;

    const bool aok = (m0 + lrow) < M;
    const float* Ap = A + (size_t)(m0 + lrow) * K + lk;
    const float* Wp = W + (size_t)(n0 + lrow) * K + lk;

    for (int k0 = 0; k0 < K; k0 += BK) {
        float4 av = make_float4(0.f, 0.f, 0.f, 0.f);
        if (aok) av = *reinterpret_cast<const float4*>(Ap + k0);
        float4 wv = *reinterpret_cast<const float4*>(Wp + k0);
        As[lk + 0][lrow] = av.x; As[lk + 1][lrow] = av.y;
        As[lk + 2][lrow] = av.z; As[lk + 3][lrow] = av.w;
        Ws[lk + 0][lrow] = wv.x; Ws[lk + 1][lrow] = wv.y;
        Ws[lk + 2][lrow] = wv.z; Ws[lk + 3][lrow] = wv.w;
        __syncthreads();
#pragma unroll
        for (int kk = 0; kk < BK; kk++) {
            float4 a4 = *reinterpret_cast<const float4*>(&As[kk][ty << 2]);
            float4 w4 = *reinterpret_cast<const float4*>(&Ws[kk][tx << 2]);
            float a[4] = {a4.x, a4.y, a4.z, a4.w};
            float w[4] = {w4.x, w4.y, w4.z, w4.w};
#pragma unroll
            for (int i = 0; i < 4; i++)
#pragma unroll
                for (int j = 0; j < 4; j++)
                    acc[i][j] = fmaf(a[i], w[j], acc[i][j]);
        }
        __syncthreads();
    }

    float4 b4 = *reinterpret_cast<const float4*>(bias + n0 + (tx << 2));
#pragma unroll
    for (int i = 0; i < 4; i++) {
        int row = m0 + (ty << 2) + i;
        if (row < M) {
            float4 o;
            o.x = acc[i][0] + b4.x; o.y = acc[i][1] + b4.y;
            o.z = acc[i][2] + b4.z; o.w = acc[i][3] + b4.w;
            *reinterpret_cast<float4*>(C + (size_t)row * N + n0 + (tx << 2)) = o;
        }
    }
}

// ---------------------------------------------------------------------------
// MFMA flash self-attention, bf16 in/out, f32 softmax.
// grid: (40 q-tiles, B*H), 256 threads = 4 waves; wave w owns q-rows w*16..+16.
// Swapped operands: S^T = mfma(K_frag, Q_frag)  -> keys lane-local (rows),
//                   O^T = mfma(V^T_frag, P_frag)-> q stats indexed by lane&15.
// V staged transposed in double-buffered LDS (1 barrier/tile, prefetched);
// K frags register-prefetched one tile ahead; P via per-wave LDS (b64 packed).
// ---------------------------------------------------------------------------
#define QT 64
#define KTT 64
#define NTQ ((NQ + QT - 1) / QT)    // 40
#define NTK ((NQ + KTT - 1) / KTT)  // 40
#define VLD (KTT + 8)               // 72

__global__ __launch_bounds__(256) void flash_mfma(const unsigned short* __restrict__ Q,
                                                  const unsigned short* __restrict__ K,
                                                  const unsigned short* __restrict__ V,
                                                  unsigned short* __restrict__ O) {
    __shared__ __align__(16) unsigned short VT[2][DH][VLD];   // V^T [buf][32][72]
    __shared__ __align__(16) unsigned short PL[4][16][VLD];   // per-wave P [16][72]

    const int bh = blockIdx.y;
    const int b = bh >> 3, h = bh & 7;
    const int t = threadIdx.x;
    const int w = t >> 6;
    const int lane = t & 63;
    const int l15 = lane & 15;
    const int g = lane >> 4;       // 0..3
    const int q0 = blockIdx.x * QT;
    const float scale = 0.17677669529663687f;   // 1/sqrt(32)

    const size_t kvb = (size_t)b * NQ * CC + h * DH;

    // Q fragment (B-operand of S^T): Q[q0+w*16+l15][g*8..+8], held all kernel
    int qr = q0 + w * 16 + l15; if (qr >= NQ) qr = NQ - 1;
    const bf16x8 qfrag = *reinterpret_cast<const bf16x8*>(Q + kvb + (size_t)qr * CC + g * 8);

    // staging map for V: thread t -> key kt*64 + (t>>2), d-block (t&3)*8
    const int skey = t >> 2;
    const int sd0  = (t & 3) << 3;

    // ---- prologue: stage V tile 0 into buf 0, preload K frags tile 0 ----
    {
        int kr = skey; if (kr >= NQ) kr = NQ - 1;
        bf16x8 vv = *reinterpret_cast<const bf16x8*>(V + kvb + (size_t)kr * CC + sd0);
#pragma unroll
        for (int j2 = 0; j2 < 8; j2++) VT[0][sd0 + j2][skey] = (unsigned short)vv[j2];
    }
    bf16x8 kf[4];
#pragma unroll
    for (int j = 0; j < 4; j++) {
        int kr = j * 16 + l15; if (kr >= NQ) kr = NQ - 1;
        kf[j] = *reinterpret_cast<const bf16x8*>(K + kvb + (size_t)kr * CC + g * 8);
    }
    __syncthreads();

    float m = -1e30f, l = 0.f;
    f32x4 o0 = {0.f, 0.f, 0.f, 0.f}, o1 = {0.f, 0.f, 0.f, 0.f};

    for (int kt = 0; kt < NTK; kt++) {
        const int cur = kt & 1;

        // ---- issue next V tile staging (lands under compute) ----
        if (kt + 1 < NTK) {
            int kr = (kt + 1) * KTT + skey; if (kr >= NQ) kr = NQ - 1;
            bf16x8 vv = *reinterpret_cast<const bf16x8*>(V + kvb + (size_t)kr * CC + sd0);
#pragma unroll
            for (int j2 = 0; j2 < 8; j2++) VT[cur ^ 1][sd0 + j2][skey] = (unsigned short)vv[j2];
        }

        // ---- S^T = K-tile . Q^T  (4 MFMAs, K dim = DH = 32) ----
        f32x4 sf[4];
#pragma unroll
        for (int j = 0; j < 4; j++)
            sf[j] = __builtin_amdgcn_mfma_f32_16x16x32_bf16(kf[j], qfrag,
                                                            (f32x4){0.f, 0.f, 0.f, 0.f}, 0, 0, 0);

        // ---- prefetch K frags for next tile ----
        if (kt + 1 < NTK) {
#pragma unroll
            for (int j = 0; j < 4; j++) {
                int kr = (kt + 1) * KTT + j * 16 + l15; if (kr >= NQ) kr = NQ - 1;
                kf[j] = *reinterpret_cast<const bf16x8*>(K + kvb + (size_t)kr * CC + g * 8);
            }
        }

        // ---- scale + mask (lane-local keys: key = kt*64 + j*16 + g*4 + r) ----
        float sv[16];
#pragma unroll
        for (int j = 0; j < 4; j++)
#pragma unroll
            for (int r = 0; r < 4; r++) {
                int key = kt * KTT + j * 16 + g * 4 + r;
                sv[j * 4 + r] = (key < NQ) ? sf[j][r] * scale : -1e30f;
            }

        // ---- online softmax for q-col l15: in-lane reduce + 2 shfl ----
        float mx = sv[0];
#pragma unroll
        for (int i = 1; i < 16; i++) mx = fmaxf(mx, sv[i]);
        mx = fmaxf(mx, __shfl_xor(mx, 16));
        mx = fmaxf(mx, __shfl_xor(mx, 32));
        float mn = fmaxf(m, mx);
        float cor = __expf(m - mn);
        m = mn;

        float ps = 0.f;
#pragma unroll
        for (int j = 0; j < 4; j++) {
            ushort4 pk;
            float p0 = __expf(sv[j * 4 + 0] - mn);
            float p1 = __expf(sv[j * 4 + 1] - mn);
            float p2 = __expf(sv[j * 4 + 2] - mn);
            float p3 = __expf(sv[j * 4 + 3] - mn);
            ps += (p0 + p1) + (p2 + p3);
            pk.x = f2b(p0); pk.y = f2b(p1); pk.z = f2b(p2); pk.w = f2b(p3);
            // P[q=l15][key j*16 + g*4 .. +4]  (packed b64 write, per-wave region)
            *reinterpret_cast<ushort4*>(&PL[w][l15][j * 16 + g * 4]) = pk;
        }
        ps += __shfl_xor(ps, 16);
        ps += __shfl_xor(ps, 32);
        l = l * cor + ps;
        o0 *= cor; o1 *= cor;

        // ---- O^T += V^T . P^T  (2 k-steps x 2 d-blocks = 4 MFMAs) ----
#pragma unroll
        for (int ks = 0; ks < 2; ks++) {
            bf16x8 pf = *reinterpret_cast<const bf16x8*>(&PL[w][l15][ks * 32 + g * 8]);
            bf16x8 va = *reinterpret_cast<const bf16x8*>(&VT[cur][l15][ks * 32 + g * 8]);
            bf16x8 vc = *reinterpret_cast<const bf16x8*>(&VT[cur][16 + l15][ks * 32 + g * 8]);
            o0 = __builtin_amdgcn_mfma_f32_16x16x32_bf16(va, pf, o0, 0, 0, 0);
            o1 = __builtin_amdgcn_mfma_f32_16x16x32_bf16(vc, pf, o1, 0, 0, 0);
        }

        __syncthreads();   // staging visible for kt+1; VT[cur] reads done
    }

    // ---- store O (lane holds O^T[d][q=l15]; d = db*16 + g*4 + r) ----
    int q = q0 + w * 16 + l15;
    if (q < NQ) {
        float inv = 1.f / l;
        unsigned short* op = O + ((size_t)b * NQ + q) * CC + h * DH;
#pragma unroll
        for (int r = 0; r < 4; r++) {
            op[g * 4 + r]      = f2b(o0[r] * inv);
            op[16 + g * 4 + r] = f2b(o1[r] * inv);
        }
    }
}

// ---------------------------------------------------------------------------
// fused residual + LayerNorm (optional bf16 copy of ln_out)
// ---------------------------------------------------------------------------
__global__ __launch_bounds__(256) void resid_ln(const float* __restrict__ a,
                                                const float* __restrict__ r,
                                                const float* __restrict__ g,
                                                const float* __restrict__ be,
                                                float* __restrict__ sum_out,
                                                float* __restrict__ ln_out,
                                                unsigned short* __restrict__ ln_bf) {
    const int row = blockIdx.x;
    const int t = threadIdx.x;
    const size_t base = (size_t)row * CC;
    float v = a[base + t] + r[base + t];
    if (sum_out) sum_out[base + t] = v;

    __shared__ float red[4];
    float s = v;
#pragma unroll
    for (int o = 1; o < 64; o <<= 1) s += __shfl_xor(s, o, 64);
    if ((t & 63) == 0) red[t >> 6] = s;
    __syncthreads();
    float mean = (red[0] + red[1] + red[2] + red[3]) * (1.f / 256.f);
    __syncthreads();

    float d = v - mean;
    float sq = d * d;
#pragma unroll
    for (int o = 1; o < 64; o <<= 1) sq += __shfl_xor(sq, o, 64);
    if ((t & 63) == 0) red[t >> 6] = sq;
    __syncthreads();
    float var = (red[0] + red[1] + red[2] + red[3]) * (1.f / 256.f);

    float res = d * rsqrtf(var + 1e-5f) * g[t] + be[t];
    ln_out[base + t] = res;
    if (ln_bf) ln_bf[base + t] = f2b(res);
}

// ---------------------------------------------------------------------------
// deformable sampling: val bf16 -> out bf16
// ---------------------------------------------------------------------------
__global__ __launch_bounds__(256) void deform_sample(const unsigned short* __restrict__ val,
                                                     const float* __restrict__ off,
                                                     const float* __restrict__ awl,
                                                     const float* __restrict__ ref,
                                                     unsigned short* __restrict__ out) {
    const int bq = blockIdx.x;
    const int b = bq / NQ;
    const int t = threadIdx.x;
    const int h = t >> 5, d = t & 31;

    const float rx = ref[(size_t)bq * 2 + 0];
    const float ry = ref[(size_t)bq * 2 + 1];

    const float* ap = awl + (size_t)bq * (HH * PP) + h * PP;
    float aw[PP];
    float mx = -1e30f;
#pragma unroll
    for (int p = 0; p < PP; p++) { aw[p] = ap[p]; mx = fmaxf(mx, aw[p]); }
    float se = 0.f;
#pragma unroll
    for (int p = 0; p < PP; p++) { aw[p] = __expf(aw[p] - mx); se += aw[p]; }
    const float inv = 1.f / se;

    const float* op = off + (size_t)bq * (HH * PP * 2) + h * (PP * 2);
    const unsigned short* vb = val + (size_t)b * NVAL * CC + h * DH + d;

    float acc = 0.f;
#pragma unroll
    for (int p = 0; p < PP; p++) {
        float x = (rx + op[p * 2 + 0] * (1.f / BEV)) * (float)BEV - 0.5f;
        float y = (ry + op[p * 2 + 1] * (1.f / BEV)) * (float)BEV - 0.5f;
        float xf = floorf(x), yf = floorf(y);
        float lx = x - xf, ly = y - yf;
        int x0 = (int)xf, y0 = (int)yf;
        float w = aw[p] * inv;

        float s = 0.f;
#pragma unroll
        for (int c = 0; c < 4; c++) {
            int xi = x0 + (c & 1);
            int yi = y0 + (c >> 1);
            float wx = (c & 1) ? lx : (1.f - lx);
            float wy = (c >> 1) ? ly : (1.f - ly);
            bool vld = (xi >= 0) && (xi < BEV) && (yi >= 0) && (yi < BEV);
            int xc = min(max(xi, 0), BEV - 1);
            int yc = min(max(yi, 0), BEV - 1);
            float gv = b2f(vb[(size_t)(yc * BEV + xc) * CC]);
            s += vld ? (wx * wy * gv) : 0.f;
        }
        acc = fmaf(w, s, acc);
    }
    out[(size_t)bq * CC + t] = f2b(acc);
}

// ---------------------------------------------------------------------------
extern "C" void kernel_launch(void* const* d_in, const int* in_sizes, int n_in,
                              void* d_out, int out_size, void* d_ws, size_t ws_size,
                              hipStream_t stream) {
    const float* query   = (const float*)d_in[0];
    const float* value   = (const float*)d_in[1];
    const float* qpos    = (const float*)d_in[2];
    const float* ref2d   = (const float*)d_in[3];
    const float* in_w    = (const float*)d_in[4];
    const float* in_b    = (const float*)d_in[5];
    const float* outp_w  = (const float*)d_in[6];
    const float* outp_b  = (const float*)d_in[7];
    const float* off_w   = (const float*)d_in[8];
    const float* off_b   = (const float*)d_in[9];
    const float* aw_w    = (const float*)d_in[10];
    const float* aw_b    = (const float*)d_in[11];
    const float* vproj_w = (const float*)d_in[12];
    const float* vproj_b = (const float*)d_in[13];
    const float* oproj_w = (const float*)d_in[14];
    const float* oproj_b = (const float*)d_in[15];
    const float* ffn_w1  = (const float*)d_in[16];
    const float* ffn_b1  = (const float*)d_in[17];
    const float* ffn_w2  = (const float*)d_in[18];
    const float* ffn_b2  = (const float*)d_in[19];
    const float* ln1_g = (const float*)d_in[20], *ln1_b = (const float*)d_in[21];
    const float* ln2_g = (const float*)d_in[22], *ln2_b = (const float*)d_in[23];
    const float* ln3_g = (const float*)d_in[24], *ln3_b = (const float*)d_in[25];

    float* ws = (float*)d_ws;
    float* out = (float*)d_out;

    const int M = BB * NQ;                 // 10000

    // ---- workspace layout (float units; bf16 buffers take half) ----
    // Region1 [0, 20.48M fl): phase-A scratch; later overlaid by VALUEb
    unsigned short* QPb    = (unsigned short*)ws;              // 1.28M fl
    unsigned short* QUERYb = (unsigned short*)(ws + 1280000);  // 1.28M fl
    unsigned short* Qbb    = (unsigned short*)(ws + 2560000);  // 1.28M fl (bf16)
    unsigned short* Kbb    = (unsigned short*)(ws + 3840000);
    unsigned short* Vbb    = (unsigned short*)(ws + 5120000);
    unsigned short* ATTb   = (unsigned short*)(ws + 6400000);
    float* SA   = ws + 7680000;                                // 2.56M fl -> ends 10.24M
    unsigned short* VALUEb = (unsigned short*)ws;              // 40.96M ush (after above die)
    // Region2 [20.48M, 40.96M fl): VALb (bf16)
    unsigned short* VALb = (unsigned short*)(ws + 20480000);
    // Region3 [40.96M, ...):
    float* B3   = ws + 40960000;
    float* X1   = B3;
    float* XLN1 = B3 + 2560000;
    float* OFF  = B3 + 5120000;
    float* AWL  = B3 + 6400000;
    unsigned short* SAMPb = (unsigned short*)(B3 + 7040000);
    float* CA   = B3 + 8320000;
    float* XLN2 = B3 + 10880000;
    unsigned short* XLN2b = (unsigned short*)(B3 + 13440000);
    unsigned short* FFNHb = (unsigned short*)(B3 + 14720000);
    float* FFNO = B3 + 17280000;
    unsigned short* Wb = (unsigned short*)(B3 + 19840000);     // 1.31M ush

    dim3 blk(256);
    const int mgT = (M + TM - 1) / TM;    // 79

    // 1. bf16 conversions
    add_cvt_qp<<<dim3(2500), blk, 0, stream>>>(query, qpos, QPb, QUERYb, 640000);
    cvt_weights<<<dim3(640), blk, 0, stream>>>(in_w, outp_w, vproj_w, oproj_w, ffn_w1, ffn_w2, Wb);
    // 2-4. q, k, v projections (bf16 MFMA, bf16 out)
    gemm_mfma<false, true><<<dim3(2, mgT), blk, 0, stream>>>(QPb,    Wb,          in_b,        nullptr, Qbb, M, CC, CC);
    gemm_mfma<false, true><<<dim3(2, mgT), blk, 0, stream>>>(QUERYb, Wb + 65536,  in_b + CC,   nullptr, Kbb, M, CC, CC);
    gemm_mfma<false, true><<<dim3(2, mgT), blk, 0, stream>>>(QUERYb, Wb + 131072, in_b + 2*CC, nullptr, Vbb, M, CC, CC);
    // 5. MFMA flash self-attention -> bf16
    flash_mfma<<<dim3(NTQ, BB * HH), blk, 0, stream>>>(Qbb, Kbb, Vbb, ATTb);
    // 6. out_proj
    gemm_mfma<false, false><<<dim3(2, mgT), blk, 0, stream>>>(ATTb, Wb + 196608, outp_b, SA, nullptr, M, CC, CC);
    // 7. x1 = sa + query; xln1 = LN1(x1)
    resid_ln<<<dim3(M), blk, 0, stream>>>(SA, query, ln1_g, ln1_b, X1, XLN1, nullptr);
    // 8-9. offsets + aw logits (fp32 small GEMMs)
    gemm_bias<<<dim3(2, (M + BM - 1) / BM), blk, 0, stream>>>(XLN1, off_w, off_b, OFF, M, 128, CC);
    gemm_bias<<<dim3(1, (M + BM - 1) / BM), blk, 0, stream>>>(XLN1, aw_w,  aw_b,  AWL, M, 64,  CC);
    // 10. value -> bf16  (region1 now dead)
    cvt4<<<dim3(40000), blk, 0, stream>>>(value, VALUEb, 10240000);
    // 11. value projection (bf16 MFMA, bf16 out)
    gemm_mfma<false, true><<<dim3(2, (BB * NVAL) / TM), blk, 0, stream>>>(VALUEb, Wb + 262144, vproj_b, nullptr, VALb, BB * NVAL, CC, CC);
    // 12. bilinear sampling -> bf16
    deform_sample<<<dim3(M), blk, 0, stream>>>(VALb, OFF, AWL, ref2d, SAMPb);
    // 13. output projection of deform attn
    gemm_mfma<false, false><<<dim3(2, mgT), blk, 0, stream>>>(SAMPb, Wb + 327680, oproj_b, CA, nullptr, M, CC, CC);
    // 14. x2 = ca + x1; xln2 = LN2(x2) (+bf16 copy)
    resid_ln<<<dim3(M), blk, 0, stream>>>(CA, X1, ln2_g, ln2_b, nullptr, XLN2, XLN2b);
    // 15-16. FFN (bf16 MFMA; hidden kept bf16 with fused ReLU)
    gemm_mfma<true,  true ><<<dim3(4, mgT), blk, 0, stream>>>(XLN2b, Wb + 393216, ffn_b1, nullptr, FFNHb, M, DFFN, CC);
    gemm_mfma<false, false><<<dim3(2, mgT), blk, 0, stream>>>(FFNHb, Wb + 524288, ffn_b2, FFNO, nullptr, M, CC, DFFN);
    // 17. out = LN3(ffn_out + xln2)
    resid_ln<<<dim3(M), blk, 0, stream>>>(FFNO, XLN2, ln3_g, ln3_b, nullptr, out, nullptr);
}

// Round 6
// 639.018 us; speedup vs baseline: 3.7994x; 1.0655x over previous
//
#include <hip/hip_runtime.h>

#define BB   4
#define NQ   2500
#define CC   256
#define HH   8
#define PP   8
#define DFFN 512
#define DH   32
#define BEV  200
#define NVAL (BEV * BEV)

typedef short bf16x8 __attribute__((ext_vector_type(8)));
typedef unsigned short u16x8 __attribute__((ext_vector_type(8)));
typedef float f32x4  __attribute__((ext_vector_type(4)));

__device__ __forceinline__ unsigned short f2b(float f) {
    union { float f; unsigned int u; } v; v.f = f;
    unsigned int r = v.u + 0x7fffu + ((v.u >> 16) & 1u);   // RNE
    return (unsigned short)(r >> 16);
}
__device__ __forceinline__ float b2f(unsigned short b) {
    union { unsigned int u; float f; } v; v.u = ((unsigned int)b) << 16;
    return v.f;
}

#define GLOAD16(g, l)                                                         \
    __builtin_amdgcn_global_load_lds(                                         \
        (const __attribute__((address_space(1))) void*)(g),                   \
        (__attribute__((address_space(3))) void*)(l), 16, 0, 0)

// ---------------------------------------------------------------------------
// fused (query+qpos)->bf16 and query->bf16
// ---------------------------------------------------------------------------
__global__ __launch_bounds__(256) void add_cvt_qp(const float* __restrict__ q,
                                                  const float* __restrict__ p,
                                                  unsigned short* __restrict__ qpb,
                                                  unsigned short* __restrict__ qb,
                                                  int n4) {
    int i = blockIdx.x * 256 + threadIdx.x;
    if (i < n4) {
        float4 a = reinterpret_cast<const float4*>(q)[i];
        float4 b = reinterpret_cast<const float4*>(p)[i];
        ushort4 s, t;
        s.x = f2b(a.x); s.y = f2b(a.y); s.z = f2b(a.z); s.w = f2b(a.w);
        t.x = f2b(a.x + b.x); t.y = f2b(a.y + b.y);
        t.z = f2b(a.z + b.z); t.w = f2b(a.w + b.w);
        reinterpret_cast<ushort4*>(qb)[i]  = s;
        reinterpret_cast<ushort4*>(qpb)[i] = t;
    }
}

// all weight matrices -> one bf16 arena (f4-index ranges hardcoded)
__global__ __launch_bounds__(256) void cvt_weights(const float* __restrict__ in_w,
                                                   const float* __restrict__ outp_w,
                                                   const float* __restrict__ vproj_w,
                                                   const float* __restrict__ oproj_w,
                                                   const float* __restrict__ ffn_w1,
                                                   const float* __restrict__ ffn_w2,
                                                   const float* __restrict__ off_w,
                                                   const float* __restrict__ aw_w,
                                                   unsigned short* __restrict__ Wb) {
    int i = blockIdx.x * 256 + threadIdx.x;      // float4 index, < 176128
    if (i >= 176128) return;
    const float* src; int base;
    if      (i <  49152) { src = in_w;    base = 0;      }
    else if (i <  65536) { src = outp_w;  base = 49152;  }
    else if (i <  81920) { src = vproj_w; base = 65536;  }
    else if (i <  98304) { src = oproj_w; base = 81920;  }
    else if (i < 131072) { src = ffn_w1;  base = 98304;  }
    else if (i < 163840) { src = ffn_w2;  base = 131072; }
    else if (i < 172032) { src = off_w;   base = 163840; }
    else                 { src = aw_w;    base = 172032; }
    float4 a = reinterpret_cast<const float4*>(src)[i - base];
    ushort4 s;
    s.x = f2b(a.x); s.y = f2b(a.y); s.z = f2b(a.z); s.w = f2b(a.w);
    reinterpret_cast<ushort4*>(Wb)[i] = s;
}

// ---------------------------------------------------------------------------
// bf16 MFMA GEMM: C[M,N] = A[M,K](bf16) @ W[N,K](bf16)^T + bias(f32)
// 128x128 tile, BK=32, 4 waves (2x2), each wave 64x64 = 4x4 frags 16x16x32.
// ---------------------------------------------------------------------------
#define TM 128
#define TN 128
#define TK 32
template <bool RELU, bool OBF>
__global__ __launch_bounds__(256) void gemm_mfma(const unsigned short* __restrict__ A,
                                                 const unsigned short* __restrict__ W,
                                                 const float* __restrict__ bias,
                                                 float* __restrict__ Cf,
                                                 unsigned short* __restrict__ Cb,
                                                 int M, int N, int K) {
    __shared__ __align__(16) unsigned short As[TM * TK];
    __shared__ __align__(16) unsigned short Ws[TN * TK];
    const int t    = threadIdx.x;
    const int lane = t & 63;
    const int wv   = t >> 6;
    const int wr   = wv >> 1;
    const int wc   = wv & 1;
    const int m0 = blockIdx.y * TM;
    const int n0 = blockIdx.x * TN;
    const int l15 = lane & 15;
    const int l4  = lane >> 4;

    const int srow = (lane >> 2);
    const int skk  = (lane & 3) << 3;

    f32x4 acc[4][4];
#pragma unroll
    for (int i = 0; i < 4; i++)
#pragma unroll
        for (int j = 0; j < 4; j++) acc[i][j] = (f32x4){0.f, 0.f, 0.f, 0.f};

    for (int k0 = 0; k0 < K; k0 += TK) {
#pragma unroll
        for (int c2 = 0; c2 < 2; c2++) {
            const int c = wv * 2 + c2;
            const int row = c * 16 + srow;
            int ar = m0 + row; if (ar >= M) ar = M - 1;
            int br = n0 + row; if (br >= N) br = N - 1;
            GLOAD16(A + (size_t)ar * K + k0 + skk, As + c * 512);
            GLOAD16(W + (size_t)br * K + k0 + skk, Ws + c * 512);
        }
        __syncthreads();

        bf16x8 af[4], bfr[4];
#pragma unroll
        for (int i = 0; i < 4; i++) {
            af[i]  = *reinterpret_cast<const bf16x8*>(&As[(wr * 64 + i * 16 + l15) * TK + l4 * 8]);
            bfr[i] = *reinterpret_cast<const bf16x8*>(&Ws[(wc * 64 + i * 16 + l15) * TK + l4 * 8]);
        }
#pragma unroll
        for (int i = 0; i < 4; i++)
#pragma unroll
            for (int j = 0; j < 4; j++)
                acc[i][j] = __builtin_amdgcn_mfma_f32_16x16x32_bf16(af[i], bfr[j], acc[i][j], 0, 0, 0);
        __syncthreads();
    }

#pragma unroll
    for (int i = 0; i < 4; i++) {
#pragma unroll
        for (int j = 0; j < 4; j++) {
            const int col = n0 + wc * 64 + j * 16 + l15;
            const float bv = bias[col];
#pragma unroll
            for (int r = 0; r < 4; r++) {
                const int row = m0 + wr * 64 + i * 16 + l4 * 4 + r;
                if (row < M) {
                    float v = acc[i][j][r] + bv;
                    if (RELU) v = fmaxf(v, 0.f);
                    if (OBF) Cb[(size_t)row * N + col] = f2b(v);
                    else     Cf[(size_t)row * N + col] = v;
                }
            }
        }
    }
}

// ---------------------------------------------------------------------------
// vproj GEMM with fused f32->bf16 A conversion (A = value, f32).
// A reg-staged into padded LDS (rows of 40 ush); W via global_load_lds.
// ---------------------------------------------------------------------------
#define VP_LDA 40
__global__ __launch_bounds__(256) void gemm_vproj(const float* __restrict__ A,
                                                  const unsigned short* __restrict__ W,
                                                  const float* __restrict__ bias,
                                                  unsigned short* __restrict__ Cb,
                                                  int M, int N, int K) {
    __shared__ __align__(16) unsigned short As[TM * VP_LDA];
    __shared__ __align__(16) unsigned short Ws[TN * TK];
    const int t    = threadIdx.x;
    const int lane = t & 63;
    const int wv   = t >> 6;
    const int wr   = wv >> 1;
    const int wc   = wv & 1;
    const int m0 = blockIdx.y * TM;
    const int n0 = blockIdx.x * TN;
    const int l15 = lane & 15;
    const int l4  = lane >> 4;
    const int srow = (lane >> 2);
    const int skk  = (lane & 3) << 3;
    const int arow = t & 127;          // A staging: row
    const int akh  = t >> 7;           // 0/1 -> k offset 0/16

    f32x4 acc[4][4];
#pragma unroll
    for (int i = 0; i < 4; i++)
#pragma unroll
        for (int j = 0; j < 4; j++) acc[i][j] = (f32x4){0.f, 0.f, 0.f, 0.f};

    int ar = m0 + arow; if (ar >= M) ar = M - 1;
    const float* ap = A + (size_t)ar * K + akh * 16;

    for (int k0 = 0; k0 < K; k0 += TK) {
        // W: async staged
#pragma unroll
        for (int c2 = 0; c2 < 2; c2++) {
            const int c = wv * 2 + c2;
            int br = n0 + c * 16 + srow; if (br >= N) br = N - 1;
            GLOAD16(W + (size_t)br * K + k0 + skk, Ws + c * 512);
        }
        // A: load 16 f32, convert, write 2x16B to padded LDS
        float4 f0 = *reinterpret_cast<const float4*>(ap + k0);
        float4 f1 = *reinterpret_cast<const float4*>(ap + k0 + 4);
        float4 f2 = *reinterpret_cast<const float4*>(ap + k0 + 8);
        float4 f3 = *reinterpret_cast<const float4*>(ap + k0 + 12);
        u16x8 pa, pb;
        pa[0] = f2b(f0.x); pa[1] = f2b(f0.y); pa[2] = f2b(f0.z); pa[3] = f2b(f0.w);
        pa[4] = f2b(f1.x); pa[5] = f2b(f1.y); pa[6] = f2b(f1.z); pa[7] = f2b(f1.w);
        pb[0] = f2b(f2.x); pb[1] = f2b(f2.y); pb[2] = f2b(f2.z); pb[3] = f2b(f2.w);
        pb[4] = f2b(f3.x); pb[5] = f2b(f3.y); pb[6] = f2b(f3.z); pb[7] = f2b(f3.w);
        *reinterpret_cast<u16x8*>(&As[arow * VP_LDA + akh * 16])     = pa;
        *reinterpret_cast<u16x8*>(&As[arow * VP_LDA + akh * 16 + 8]) = pb;
        __syncthreads();

        bf16x8 af[4], bfr[4];
#pragma unroll
        for (int i = 0; i < 4; i++) {
            af[i]  = *reinterpret_cast<const bf16x8*>(&As[(wr * 64 + i * 16 + l15) * VP_LDA + l4 * 8]);
            bfr[i] = *reinterpret_cast<const bf16x8*>(&Ws[(wc * 64 + i * 16 + l15) * TK + l4 * 8]);
        }
#pragma unroll
        for (int i = 0; i < 4; i++)
#pragma unroll
            for (int j = 0; j < 4; j++)
                acc[i][j] = __builtin_amdgcn_mfma_f32_16x16x32_bf16(af[i], bfr[j], acc[i][j], 0, 0, 0);
        __syncthreads();
    }

#pragma unroll
    for (int i = 0; i < 4; i++) {
#pragma unroll
        for (int j = 0; j < 4; j++) {
            const int col = n0 + wc * 64 + j * 16 + l15;
            const float bv = bias[col];
#pragma unroll
            for (int r = 0; r < 4; r++) {
                const int row = m0 + wr * 64 + i * 16 + l4 * 4 + r;
                if (row < M)
                    Cb[(size_t)row * N + col] = f2b(acc[i][j][r] + bv);
            }
        }
    }
}

// ---------------------------------------------------------------------------
// off+aw fused MFMA GEMM: A[M,256](bf16) @ [off_w; aw_w]^T (N=192).
// TM=128, TN=64: 4 waves 2x2, wave tile 64x32 (4x2 frags). Grid (3, 79).
// cols 0..127 -> OFF (+off_b), cols 128..191 -> AWL (+aw_b). f32 outputs.
// ---------------------------------------------------------------------------
__global__ __launch_bounds__(256) void gemm_offaw(const unsigned short* __restrict__ A,
                                                  const unsigned short* __restrict__ W,
                                                  const float* __restrict__ off_b,
                                                  const float* __restrict__ aw_b,
                                                  float* __restrict__ OFF,
                                                  float* __restrict__ AWL,
                                                  int M) {
    __shared__ __align__(16) unsigned short As[TM * TK];
    __shared__ __align__(16) unsigned short Ws[64 * TK];
    const int t    = threadIdx.x;
    const int lane = t & 63;
    const int wv   = t >> 6;
    const int wr   = wv >> 1;
    const int wc   = wv & 1;
    const int m0 = blockIdx.y * TM;
    const int n0 = blockIdx.x * 64;
    const int l15 = lane & 15;
    const int l4  = lane >> 4;
    const int srow = (lane >> 2);
    const int skk  = (lane & 3) << 3;

    f32x4 acc[4][2];
#pragma unroll
    for (int i = 0; i < 4; i++)
#pragma unroll
        for (int j = 0; j < 2; j++) acc[i][j] = (f32x4){0.f, 0.f, 0.f, 0.f};

    for (int k0 = 0; k0 < 256; k0 += TK) {
#pragma unroll
        for (int c2 = 0; c2 < 2; c2++) {
            const int c = wv * 2 + c2;
            int ar = m0 + c * 16 + srow; if (ar >= M) ar = M - 1;
            GLOAD16(A + (size_t)ar * 256 + k0 + skk, As + c * 512);
        }
        {
            int br = n0 + wv * 16 + srow;   // < 192 always
            GLOAD16(W + (size_t)br * 256 + k0 + skk, Ws + wv * 512);
        }
        __syncthreads();

        bf16x8 af[4], bw[2];
#pragma unroll
        for (int i = 0; i < 4; i++)
            af[i] = *reinterpret_cast<const bf16x8*>(&As[(wr * 64 + i * 16 + l15) * TK + l4 * 8]);
#pragma unroll
        for (int j = 0; j < 2; j++)
            bw[j] = *reinterpret_cast<const bf16x8*>(&Ws[(wc * 32 + j * 16 + l15) * TK + l4 * 8]);
#pragma unroll
        for (int i = 0; i < 4; i++)
#pragma unroll
            for (int j = 0; j < 2; j++)
                acc[i][j] = __builtin_amdgcn_mfma_f32_16x16x32_bf16(af[i], bw[j], acc[i][j], 0, 0, 0);
        __syncthreads();
    }

#pragma unroll
    for (int i = 0; i < 4; i++) {
#pragma unroll
        for (int j = 0; j < 2; j++) {
            const int gc = n0 + wc * 32 + j * 16 + l15;
            const float bv = (gc < 128) ? off_b[gc] : aw_b[gc - 128];
#pragma unroll
            for (int r = 0; r < 4; r++) {
                const int row = m0 + wr * 64 + i * 16 + l4 * 4 + r;
                if (row < M) {
                    float v = acc[i][j][r] + bv;
                    if (gc < 128) OFF[(size_t)row * 128 + gc] = v;
                    else          AWL[(size_t)row * 64 + (gc - 128)] = v;
                }
            }
        }
    }
}

// ---------------------------------------------------------------------------
// MFMA flash self-attention, split-K=2. K/V interleaved in KVb (row stride 512:
// K at 0..255, V at 256..511). PART/ML partials, combined by flash_combine.
// grid: (40 q-tiles, 32 bh, 2 chunks), 256 threads = 4 waves.
// ---------------------------------------------------------------------------
#define QT 64
#define KTT 64
#define NTQ ((NQ + QT - 1) / QT)    // 40
#define CHK 1280
#define NTK2 (CHK / KTT)            // 20
#define VLD (KTT + 8)               // 72

__global__ __launch_bounds__(256) void flash_part(const unsigned short* __restrict__ Q,
                                                  const unsigned short* __restrict__ KV,
                                                  float* __restrict__ PART,
                                                  float* __restrict__ ML) {
    __shared__ __align__(16) unsigned short VT[2][DH][VLD];   // V^T [buf][32][72]
    __shared__ __align__(16) unsigned short PL[4][16][VLD];   // per-wave P [16][72]

    const int c  = blockIdx.z;
    const int bh = blockIdx.y;
    const int b = bh >> 3, h = bh & 7;
    const int t = threadIdx.x;
    const int w = t >> 6;
    const int lane = t & 63;
    const int l15 = lane & 15;
    const int g = lane >> 4;       // 0..3
    const int q0 = blockIdx.x * QT;
    const int kc0 = c * CHK;
    const float scale = 0.17677669529663687f;   // 1/sqrt(32)

    const size_t qbase = (size_t)b * NQ;

    int qr = q0 + w * 16 + l15; if (qr >= NQ) qr = NQ - 1;
    const bf16x8 qfrag = *reinterpret_cast<const bf16x8*>(Q + (qbase + qr) * CC + h * DH + g * 8);

    const int skey = t >> 2;
    const int sd0  = (t & 3) << 3;

    // prologue: stage V tile 0 of this chunk; preload K frags
    {
        int kr = kc0 + skey; if (kr >= NQ) kr = NQ - 1;
        bf16x8 vv = *reinterpret_cast<const bf16x8*>(KV + (qbase + kr) * 512 + 256 + h * DH + sd0);
#pragma unroll
        for (int j2 = 0; j2 < 8; j2++) VT[0][sd0 + j2][skey] = (unsigned short)vv[j2];
    }
    bf16x8 kf[4];
#pragma unroll
    for (int j = 0; j < 4; j++) {
        int kr = kc0 + j * 16 + l15; if (kr >= NQ) kr = NQ - 1;
        kf[j] = *reinterpret_cast<const bf16x8*>(KV + (qbase + kr) * 512 + h * DH + g * 8);
    }
    __syncthreads();

    float m = -1e30f, l = 0.f;
    f32x4 o0 = {0.f, 0.f, 0.f, 0.f}, o1 = {0.f, 0.f, 0.f, 0.f};

    for (int kt = 0; kt < NTK2; kt++) {
        const int cur = kt & 1;

        if (kt + 1 < NTK2) {
            int kr = kc0 + (kt + 1) * KTT + skey; if (kr >= NQ) kr = NQ - 1;
            bf16x8 vv = *reinterpret_cast<const bf16x8*>(KV + (qbase + kr) * 512 + 256 + h * DH + sd0);
#pragma unroll
            for (int j2 = 0; j2 < 8; j2++) VT[cur ^ 1][sd0 + j2][skey] = (unsigned short)vv[j2];
        }

        f32x4 sf[4];
#pragma unroll
        for (int j = 0; j < 4; j++)
            sf[j] = __builtin_amdgcn_mfma_f32_16x16x32_bf16(kf[j], qfrag,
                                                            (f32x4){0.f, 0.f, 0.f, 0.f}, 0, 0, 0);

        if (kt + 1 < NTK2) {
#pragma unroll
            for (int j = 0; j < 4; j++) {
                int kr = kc0 + (kt + 1) * KTT + j * 16 + l15; if (kr >= NQ) kr = NQ - 1;
                kf[j] = *reinterpret_cast<const bf16x8*>(KV + (qbase + kr) * 512 + h * DH + g * 8);
            }
        }

        float sv[16];
#pragma unroll
        for (int j = 0; j < 4; j++)
#pragma unroll
            for (int r = 0; r < 4; r++) {
                int key = kc0 + kt * KTT + j * 16 + g * 4 + r;
                sv[j * 4 + r] = (key < NQ) ? sf[j][r] * scale : -1e30f;
            }

        float mx = sv[0];
#pragma unroll
        for (int i = 1; i < 16; i++) mx = fmaxf(mx, sv[i]);
        mx = fmaxf(mx, __shfl_xor(mx, 16));
        mx = fmaxf(mx, __shfl_xor(mx, 32));
        float mn = fmaxf(m, mx);
        float cor = __expf(m - mn);
        m = mn;

        float ps = 0.f;
#pragma unroll
        for (int j = 0; j < 4; j++) {
            ushort4 pk;
            float p0 = __expf(sv[j * 4 + 0] - mn);
            float p1 = __expf(sv[j * 4 + 1] - mn);
            float p2 = __expf(sv[j * 4 + 2] - mn);
            float p3 = __expf(sv[j * 4 + 3] - mn);
            ps += (p0 + p1) + (p2 + p3);
            pk.x = f2b(p0); pk.y = f2b(p1); pk.z = f2b(p2); pk.w = f2b(p3);
            *reinterpret_cast<ushort4*>(&PL[w][l15][j * 16 + g * 4]) = pk;
        }
        ps += __shfl_xor(ps, 16);
        ps += __shfl_xor(ps, 32);
        l = l * cor + ps;
        o0 *= cor; o1 *= cor;

#pragma unroll
        for (int ks = 0; ks < 2; ks++) {
            bf16x8 pf = *reinterpret_cast<const bf16x8*>(&PL[w][l15][ks * 32 + g * 8]);
            bf16x8 va = *reinterpret_cast<const bf16x8*>(&VT[cur][l15][ks * 32 + g * 8]);
            bf16x8 vc = *reinterpret_cast<const bf16x8*>(&VT[cur][16 + l15][ks * 32 + g * 8]);
            o0 = __builtin_amdgcn_mfma_f32_16x16x32_bf16(va, pf, o0, 0, 0, 0);
            o1 = __builtin_amdgcn_mfma_f32_16x16x32_bf16(vc, pf, o1, 0, 0, 0);
        }

        __syncthreads();
    }

    int q = q0 + w * 16 + l15;
    if (q < NQ) {
        float* pp = PART + ((size_t)(c * (BB * HH) + bh) * NQ + q) * 32;
        *reinterpret_cast<f32x4*>(pp + g * 4)      = o0;
        *reinterpret_cast<f32x4*>(pp + 16 + g * 4) = o1;
        if (g == 0) {
            float* mp = ML + ((size_t)(c * (BB * HH) + bh) * NQ + q) * 2;
            mp[0] = m; mp[1] = l;
        }
    }
}

// combine 2 chunks -> bf16 O (B, NQ, C)
__global__ __launch_bounds__(256) void flash_combine(const float* __restrict__ PART,
                                                     const float* __restrict__ ML,
                                                     unsigned short* __restrict__ O) {
    const int idx = blockIdx.x * 256 + threadIdx.x;   // < B*NQ*CC
    const int bq = idx >> 8;
    const int hd = idx & 255;
    const int h = hd >> 5, dd = hd & 31;
    const int b = bq / NQ, q = bq - b * NQ;
    const int bh = b * HH + h;

    const float* mp0 = ML + ((size_t)bh * NQ + q) * 2;
    const float* mp1 = ML + ((size_t)(32 + bh) * NQ + q) * 2;
    float m0 = mp0[0], l0 = mp0[1];
    float m1 = mp1[0], l1 = mp1[1];
    float M = fmaxf(m0, m1);
    float w0 = __expf(m0 - M), w1 = __expf(m1 - M);
    float L = w0 * l0 + w1 * l1;
    float S = w0 * PART[((size_t)bh * NQ + q) * 32 + dd]
            + w1 * PART[((size_t)(32 + bh) * NQ + q) * 32 + dd];
    O[idx] = f2b(S / L);
}

// ---------------------------------------------------------------------------
// fused residual + LayerNorm (all outputs optional)
// ---------------------------------------------------------------------------
__global__ __launch_bounds__(256) void resid_ln(const float* __restrict__ a,
                                                const float* __restrict__ r,
                                                const float* __restrict__ g,
                                                const float* __restrict__ be,
                                                float* __restrict__ sum_out,
                                                float* __restrict__ ln_out,
                                                unsigned short* __restrict__ ln_bf) {
    const int row = blockIdx.x;
    const int t = threadIdx.x;
    const size_t base = (size_t)row * CC;
    float v = a[base + t] + r[base + t];
    if (sum_out) sum_out[base + t] = v;

    __shared__ float red[4];
    float s = v;
#pragma unroll
    for (int o = 1; o < 64; o <<= 1) s += __shfl_xor(s, o, 64);
    if ((t & 63) == 0) red[t >> 6] = s;
    __syncthreads();
    float mean = (red[0] + red[1] + red[2] + red[3]) * (1.f / 256.f);
    __syncthreads();

    float d = v - mean;
    float sq = d * d;
#pragma unroll
    for (int o = 1; o < 64; o <<= 1) sq += __shfl_xor(sq, o, 64);
    if ((t & 63) == 0) red[t >> 6] = sq;
    __syncthreads();
    float var = (red[0] + red[1] + red[2] + red[3]) * (1.f / 256.f);

    float res = d * rsqrtf(var + 1e-5f) * g[t] + be[t];
    if (ln_out) ln_out[base + t] = res;
    if (ln_bf)  ln_bf[base + t] = f2b(res);
}

// ---------------------------------------------------------------------------
// deformable sampling: val bf16, off/aw f32 -> out bf16
// ---------------------------------------------------------------------------
__global__ __launch_bounds__(256) void deform_sample(const unsigned short* __restrict__ val,
                                                     const float* __restrict__ off,
                                                     const float* __restrict__ awl,
                                                     const float* __restrict__ ref,
                                                     unsigned short* __restrict__ out) {
    const int bq = blockIdx.x;
    const int b = bq / NQ;
    const int t = threadIdx.x;
    const int h = t >> 5, d = t & 31;

    const float rx = ref[(size_t)bq * 2 + 0];
    const float ry = ref[(size_t)bq * 2 + 1];

    const float* ap = awl + (size_t)bq * (HH * PP) + h * PP;
    float aw[PP];
    float mx = -1e30f;
#pragma unroll
    for (int p = 0; p < PP; p++) { aw[p] = ap[p]; mx = fmaxf(mx, aw[p]); }
    float se = 0.f;
#pragma unroll
    for (int p = 0; p < PP; p++) { aw[p] = __expf(aw[p] - mx); se += aw[p]; }
    const float inv = 1.f / se;

    const float* op = off + (size_t)bq * (HH * PP * 2) + h * (PP * 2);
    const unsigned short* vb = val + (size_t)b * NVAL * CC + h * DH + d;

    float acc = 0.f;
#pragma unroll
    for (int p = 0; p < PP; p++) {
        float x = (rx + op[p * 2 + 0] * (1.f / BEV)) * (float)BEV - 0.5f;
        float y = (ry + op[p * 2 + 1] * (1.f / BEV)) * (float)BEV - 0.5f;
        float xf = floorf(x), yf = floorf(y);
        float lx = x - xf, ly = y - yf;
        int x0 = (int)xf, y0 = (int)yf;
        float w = aw[p] * inv;

        float s = 0.f;
#pragma unroll
        for (int c = 0; c < 4; c++) {
            int xi = x0 + (c & 1);
            int yi = y0 + (c >> 1);
            float wx = (c & 1) ? lx : (1.f - lx);
            float wy = (c >> 1) ? ly : (1.f - ly);
            bool vld = (xi >= 0) && (xi < BEV) && (yi >= 0) && (yi < BEV);
            int xc = min(max(xi, 0), BEV - 1);
            int yc = min(max(yi, 0), BEV - 1);
            float gv = b2f(vb[(size_t)(yc * BEV + xc) * CC]);
            s += vld ? (wx * wy * gv) : 0.f;
        }
        acc = fmaf(w, s, acc);
    }
    out[(size_t)bq * CC + t] = f2b(acc);
}

// ---------------------------------------------------------------------------
extern "C" void kernel_launch(void* const* d_in, const int* in_sizes, int n_in,
                              void* d_out, int out_size, void* d_ws, size_t ws_size,
                              hipStream_t stream) {
    const float* query   = (const float*)d_in[0];
    const float* value   = (const float*)d_in[1];
    const float* qpos    = (const float*)d_in[2];
    const float* ref2d   = (const float*)d_in[3];
    const float* in_w    = (const float*)d_in[4];
    const float* in_b    = (const float*)d_in[5];
    const float* outp_w  = (const float*)d_in[6];
    const float* outp_b  = (const float*)d_in[7];
    const float* off_w   = (const float*)d_in[8];
    const float* off_b   = (const float*)d_in[9];
    const float* aw_w    = (const float*)d_in[10];
    const float* aw_b    = (const float*)d_in[11];
    const float* vproj_w = (const float*)d_in[12];
    const float* vproj_b = (const float*)d_in[13];
    const float* oproj_w = (const float*)d_in[14];
    const float* oproj_b = (const float*)d_in[15];
    const float* ffn_w1  = (const float*)d_in[16];
    const float* ffn_b1  = (const float*)d_in[17];
    const float* ffn_w2  = (const float*)d_in[18];
    const float* ffn_b2  = (const float*)d_in[19];
    const float* ln1_g = (const float*)d_in[20], *ln1_b = (const float*)d_in[21];
    const float* ln2_g = (const float*)d_in[22], *ln2_b = (const float*)d_in[23];
    const float* ln3_g = (const float*)d_in[24], *ln3_b = (const float*)d_in[25];

    float* ws = (float*)d_ws;
    float* out = (float*)d_out;

    const int M = BB * NQ;                 // 10000

    // ---- workspace layout (float offsets) ----
    // Region1: phase-A scratch
    unsigned short* QPb    = (unsigned short*)ws;              // [0, 1.28M)
    unsigned short* QUERYb = (unsigned short*)(ws + 1280000);
    unsigned short* Qbb    = (unsigned short*)(ws + 2560000);
    unsigned short* KVb    = (unsigned short*)(ws + 3840000);  // M x 512 ush = 2.56M fl
    unsigned short* ATTb   = (unsigned short*)(ws + 6400000);
    float* SA   = ws + 7680000;                                // 2.56M fl
    float* PART = ws + 10240000;                               // 5.12M fl
    float* ML   = ws + 15360000;                               // 0.32M fl
    // Region2: VALb
    unsigned short* VALb = (unsigned short*)(ws + 20480000);   // 40.96M ush
    // Region3:
    float* B3   = ws + 40960000;
    float* X1   = B3;                                          // 2.56M
    unsigned short* XLN1b = (unsigned short*)(B3 + 2560000);   // 1.28M fl
    float* OFF  = B3 + 3840000;                                // 1.28M
    float* AWL  = B3 + 5120000;                                // 0.64M
    unsigned short* SAMPb = (unsigned short*)(B3 + 5760000);   // 1.28M fl
    float* CA   = B3 + 7040000;                                // 2.56M
    float* XLN2 = B3 + 9600000;                                // 2.56M
    unsigned short* XLN2b = (unsigned short*)(B3 + 12160000);  // 1.28M fl
    unsigned short* FFNHb = (unsigned short*)(B3 + 13440000);  // 2.56M fl
    float* FFNO = B3 + 16000000;                               // 2.56M
    unsigned short* Wb = (unsigned short*)(B3 + 18560000);     // 0.353M fl
    // total ~59.9M floats = 239.6 MB

    dim3 blk(256);
    const int mgT = (M + TM - 1) / TM;    // 79

    // 1. bf16 conversions
    add_cvt_qp<<<dim3(2500), blk, 0, stream>>>(query, qpos, QPb, QUERYb, 640000);
    cvt_weights<<<dim3(688), blk, 0, stream>>>(in_w, outp_w, vproj_w, oproj_w,
                                               ffn_w1, ffn_w2, off_w, aw_w, Wb);
    // 2. q projection; 3. fused k+v projection (N=512, interleaved rows)
    gemm_mfma<false, true><<<dim3(2, mgT), blk, 0, stream>>>(QPb,    Wb,         in_b,       nullptr, Qbb, M, CC, CC);
    gemm_mfma<false, true><<<dim3(4, mgT), blk, 0, stream>>>(QUERYb, Wb + 65536, in_b + CC,  nullptr, KVb, M, 512, CC);
    // 4. MFMA flash self-attention, split-K=2 + combine
    flash_part<<<dim3(NTQ, BB * HH, 2), blk, 0, stream>>>(Qbb, KVb, PART, ML);
    flash_combine<<<dim3(M), blk, 0, stream>>>(PART, ML, ATTb);
    // 5. out_proj
    gemm_mfma<false, false><<<dim3(2, mgT), blk, 0, stream>>>(ATTb, Wb + 196608, outp_b, SA, nullptr, M, CC, CC);
    // 6. x1 = sa + query; xln1 -> bf16
    resid_ln<<<dim3(M), blk, 0, stream>>>(SA, query, ln1_g, ln1_b, X1, nullptr, XLN1b);
    // 7. off+aw fused MFMA GEMM (N=192)
    gemm_offaw<<<dim3(3, mgT), blk, 0, stream>>>(XLN1b, Wb + 655360, off_b, aw_b, OFF, AWL, M);
    // 8. value projection with fused f32->bf16 A conversion
    gemm_vproj<<<dim3(2, (BB * NVAL) / TM), blk, 0, stream>>>(value, Wb + 262144, vproj_b, VALb, BB * NVAL, CC, CC);
    // 9. bilinear sampling -> bf16
    deform_sample<<<dim3(M), blk, 0, stream>>>(VALb, OFF, AWL, ref2d, SAMPb);
    // 10. output projection of deform attn
    gemm_mfma<false, false><<<dim3(2, mgT), blk, 0, stream>>>(SAMPb, Wb + 327680, oproj_b, CA, nullptr, M, CC, CC);
    // 11. x2 = ca + x1; xln2 (f32 + bf16)
    resid_ln<<<dim3(M), blk, 0, stream>>>(CA, X1, ln2_g, ln2_b, nullptr, XLN2, XLN2b);
    // 12-13. FFN
    gemm_mfma<true,  true ><<<dim3(4, mgT), blk, 0, stream>>>(XLN2b, Wb + 393216, ffn_b1, nullptr, FFNHb, M, DFFN, CC);
    gemm_mfma<false, false><<<dim3(2, mgT), blk, 0, stream>>>(FFNHb, Wb + 524288, ffn_b2, FFNO, nullptr, M, CC, DFFN);
    // 14. out = LN3(ffn_out + xln2)
    resid_ln<<<dim3(M), blk, 0, stream>>>(FFNO, XLN2, ln3_g, ln3_b, nullptr, out, nullptr);
}